// Round 1
// baseline (606.143 us; speedup 1.0000x reference)
//
#include <hip/hip_runtime.h>

#define HID 64
#define POS_DIM 32
#define IN_DIM 128

// ---------------- degree ----------------
__global__ void k_init_deg(float* deg, int n) {
    int i = blockIdx.x * blockDim.x + threadIdx.x;
    if (i < n) deg[i] = 1.0f;   // self-loop
}

__global__ void k_count_deg(const int* __restrict__ tp, float* deg, int E) {
    int i = blockIdx.x * blockDim.x + threadIdx.x;
    if (i < E) atomicAdd(&deg[tp[E + i]], 1.0f);   // col = tp[1][i]
}

__global__ void k_dinv(float* deg, int n) {
    int i = blockIdx.x * blockDim.x + threadIdx.x;
    if (i < n) deg[i] = rsqrtf(deg[i]);            // deg >= 1 always
}

// ---------------- per-edge coefficients (shared sqdist/norm, both layers) ----------------
__global__ void k_coef(const int* __restrict__ tp, const float* __restrict__ pos,
                       const float* __restrict__ dinv,
                       const float* em1w, const float* em1b,
                       const float* em2w, const float* em2b,
                       float* __restrict__ coef1, float* __restrict__ coef2, int E) {
    int sub  = threadIdx.x >> 5;           // 8 edges per 256-thread block
    int lane = threadIdx.x & 31;
    int e = blockIdx.x * (blockDim.x >> 5) + sub;
    if (e >= E) return;
    int row = tp[e];
    int col = tp[E + e];
    float d  = pos[(size_t)row * POS_DIM + lane] - pos[(size_t)col * POS_DIM + lane];
    float sq = d * d;
    #pragma unroll
    for (int off = 16; off; off >>= 1) sq += __shfl_down(sq, off, 32);
    if (lane == 0) {
        float norm = dinv[row] * dinv[col];
        float g1 = 1.0f / (1.0f + expf(-(sq * em1w[0] + em1b[0])));
        float g2 = 1.0f / (1.0f + expf(-(sq * em2w[0] + em2b[0])));
        coef1[e] = g1 * norm;
        coef2[e] = g2 * norm;
    }
}

// ---------------- GEMM: H[n,64] = X[n,K] @ W[K,64] ----------------
template<int K>
__global__ __launch_bounds__(256) void k_gemm(const float* __restrict__ X,
                                              const float* __restrict__ W,
                                              float* __restrict__ H, int n) {
    __shared__ float Ws[K * HID];
    __shared__ float Xs[4 * K];
    int tid = threadIdx.x;
    for (int i = tid; i < K * HID; i += 256) Ws[i] = W[i];
    int row0 = blockIdx.x * 4;
    for (int i = tid; i < 4 * K; i += 256) {
        int r = row0 + i / K;
        Xs[i] = (r < n) ? X[(size_t)r * K + (i % K)] : 0.0f;
    }
    __syncthreads();
    int lr  = tid >> 6;       // 0..3 local row
    int col = tid & 63;
    int row = row0 + lr;
    if (row >= n) return;
    float acc = 0.0f;
    #pragma unroll
    for (int k = 0; k < K; ++k)
        acc = fmaf(Xs[lr * K + k], Ws[k * HID + col], acc);
    H[(size_t)row * HID + col] = acc;
}

// ---------------- init accumulator: bias + self-loop contribution ----------------
__global__ void k_init_out(const float* __restrict__ h, const float* __restrict__ dinv,
                           const float* __restrict__ b, const float* emb,
                           float* __restrict__ out, int n) {
    int idx = blockIdx.x * blockDim.x + threadIdx.x;
    if (idx >= n * HID) return;
    int i = idx >> 6, c = idx & 63;
    float g  = 1.0f / (1.0f + expf(-emb[0]));   // sq = 0 for self-loop
    float di = dinv[i];
    out[idx] = b[c] + g * di * di * h[idx];
}

// ---------------- edge scatter: out[col] += coef * h[row] ----------------
__global__ void k_scatter(const int* __restrict__ tp, const float* __restrict__ coef,
                          const float* __restrict__ h, float* out, int E) {
    int sub  = threadIdx.x >> 6;           // 4 edges per 256-thread block (1 wave each)
    int lane = threadIdx.x & 63;
    int e = blockIdx.x * 4 + sub;
    if (e >= E) return;
    int row = tp[e];
    int col = tp[E + e];
    float c = coef[e];
    float v = c * h[(size_t)row * HID + lane];
    atomicAdd(&out[(size_t)col * HID + lane], v);
}

// ---------------- final link predictor ----------------
__global__ void k_predict(const int* __restrict__ pei, const int* __restrict__ nei,
                          const float* __restrict__ h, const float* __restrict__ pos,
                          const float* fcw, const float* fcb,
                          float* __restrict__ out, int Elp) {
    int sub  = threadIdx.x >> 6;
    int lane = threadIdx.x & 63;
    int e = blockIdx.x * 4 + sub;
    if (e >= 2 * Elp) return;
    int src, dst;
    if (e < Elp) { src = pei[e];        dst = pei[Elp + e]; }
    else         { src = nei[e - Elp];  dst = nei[e];       }  // nei[Elp + (e-Elp)]
    float p = h[(size_t)src * HID + lane] * h[(size_t)dst * HID + lane];
    float pe = 0.0f;
    if (lane < 32) {
        float d = pos[(size_t)src * POS_DIM + lane] - pos[(size_t)dst * POS_DIM + lane];
        pe = d * d;
    }
    #pragma unroll
    for (int off = 32; off; off >>= 1) {
        p  += __shfl_down(p, off);
        pe += __shfl_down(pe, off);
    }
    if (lane == 0) out[e] = fcw[0] * p + fcw[1] * pe + fcb[0];
}

extern "C" void kernel_launch(void* const* d_in, const int* in_sizes, int n_in,
                              void* d_out, int out_size, void* d_ws, size_t ws_size,
                              hipStream_t stream) {
    const float* x    = (const float*)d_in[0];
    const float* pos  = (const float*)d_in[1];
    const int*   pei  = (const int*)d_in[2];
    const int*   nei  = (const int*)d_in[3];
    const int*   tp   = (const int*)d_in[4];
    const float* W1   = (const float*)d_in[5];
    const float* b1   = (const float*)d_in[6];
    const float* em1w = (const float*)d_in[7];
    const float* em1b = (const float*)d_in[8];
    const float* W2   = (const float*)d_in[9];
    const float* b2   = (const float*)d_in[10];
    const float* em2w = (const float*)d_in[11];
    const float* em2b = (const float*)d_in[12];
    const float* fcw  = (const float*)d_in[13];
    const float* fcb  = (const float*)d_in[14];
    float* outp = (float*)d_out;

    const int N   = in_sizes[0] / IN_DIM;   // 50000
    const int E   = in_sizes[4] / 2;        // 800000
    const int Elp = in_sizes[2] / 2;        // 100000

    float* ws    = (float*)d_ws;
    float* dinv  = ws;                        // N
    float* coef1 = dinv + N;                  // E
    float* coef2 = coef1 + E;                 // E
    float* hbuf  = coef2 + E;                 // N*64  (h1, then h2)
    float* obuf  = hbuf + (size_t)N * HID;    // N*64  (out1, then out2)

    // degree -> dinv
    k_init_deg<<<(N + 255) / 256, 256, 0, stream>>>(dinv, N);
    k_count_deg<<<(E + 255) / 256, 256, 0, stream>>>(tp, dinv, E);
    k_dinv<<<(N + 255) / 256, 256, 0, stream>>>(dinv, N);

    // per-edge coefficients for both layers
    k_coef<<<(E + 7) / 8, 256, 0, stream>>>(tp, pos, dinv, em1w, em1b, em2w, em2b,
                                            coef1, coef2, E);

    // ---- layer 1 ----
    k_gemm<IN_DIM><<<(N + 3) / 4, 256, 0, stream>>>(x, W1, hbuf, N);
    k_init_out<<<((size_t)N * HID + 255) / 256, 256, 0, stream>>>(hbuf, dinv, b1, em1b, obuf, N);
    k_scatter<<<(E + 3) / 4, 256, 0, stream>>>(tp, coef1, hbuf, obuf, E);

    // ---- layer 2 ----  (h2 = out1 @ W2 reuses hbuf; out2 reuses obuf)
    k_gemm<HID><<<(N + 3) / 4, 256, 0, stream>>>(obuf, W2, hbuf, N);
    k_init_out<<<((size_t)N * HID + 255) / 256, 256, 0, stream>>>(hbuf, dinv, b2, em2b, obuf, N);
    k_scatter<<<(E + 3) / 4, 256, 0, stream>>>(tp, coef2, hbuf, obuf, E);

    // ---- predictor ----
    k_predict<<<(2 * Elp + 3) / 4, 256, 0, stream>>>(pei, nei, obuf, pos, fcw, fcb, outp, Elp);
}

// Round 2
// 424.578 us; speedup vs baseline: 1.4276x; 1.4276x over previous
//
#include <hip/hip_runtime.h>

#define HID 64
#define POS_DIM 32
#define IN_DIM 128

__device__ __forceinline__ float sigmoidf_(float v) {
    return 1.0f / (1.0f + expf(-v));
}

// ---------------- in-degree histogram (cur doubles as cnt, later cursor) ----------------
__global__ void k_hist(const int* __restrict__ tp, int* cur, int E) {
    int i = blockIdx.x * blockDim.x + threadIdx.x;
    if (i < E) atomicAdd(&cur[tp[E + i]], 1);   // col = tp[1][i]
}

__global__ void k_dinv(const int* __restrict__ cur, float* dinv, int n) {
    int i = blockIdx.x * blockDim.x + threadIdx.x;
    if (i < n) dinv[i] = rsqrtf((float)(cur[i] + 1));   // +1 self-loop
}

// ---------------- single-block exclusive scan: off[i], and cur[i] := off[i] ----------------
__global__ __launch_bounds__(1024) void k_scan(int* cur, int* off, int n) {
    __shared__ int sums[1024];
    int t = threadIdx.x;
    int ch = (n + 1023) / 1024;
    int lo = t * ch, hi = min(lo + ch, n);
    int s = 0;
    for (int i = lo; i < hi; ++i) s += cur[i];
    sums[t] = s;
    __syncthreads();
    for (int d = 1; d < 1024; d <<= 1) {
        int v = 0;
        if (t >= d) v = sums[t - d];
        __syncthreads();
        if (t >= d) sums[t] += v;
        __syncthreads();
    }
    int run = sums[t] - s;   // exclusive prefix of this chunk
    for (int i = lo; i < hi; ++i) {
        int c = cur[i];
        off[i] = run;
        cur[i] = run;        // cursor reset
        run += c;
    }
    if (t == 1023) off[n] = sums[1023];
}

// ---------------- coef (both layers) + CSR fill ----------------
__global__ void k_coef_fill(const int* __restrict__ tp, const float* __restrict__ pos,
                            const float* __restrict__ dinv,
                            const float* em1w, const float* em1b,
                            const float* em2w, const float* em2b,
                            int* cur, int* __restrict__ csr_src,
                            float* __restrict__ c1, float* __restrict__ c2, int E) {
    int sub  = threadIdx.x >> 5;           // 8 edges per 256-thread block
    int lane = threadIdx.x & 31;
    int e = blockIdx.x * 8 + sub;
    if (e >= E) return;
    int row = tp[e];
    int col = tp[E + e];
    float d  = pos[(size_t)row * POS_DIM + lane] - pos[(size_t)col * POS_DIM + lane];
    float sq = d * d;
    #pragma unroll
    for (int off = 16; off; off >>= 1) sq += __shfl_down(sq, off, 32);
    if (lane == 0) {
        float norm = dinv[row] * dinv[col];
        int slot = atomicAdd(&cur[col], 1);
        csr_src[slot] = row;
        c1[slot] = sigmoidf_(sq * em1w[0] + em1b[0]) * norm;
        c2[slot] = sigmoidf_(sq * em2w[0] + em2b[0]) * norm;
    }
}

// ---------------- GEMM: H[n,64] = X[n,K] @ W[K,64], 32 rows/block ----------------
template<int K>
__global__ __launch_bounds__(256) void k_gemm(const float* __restrict__ X,
                                              const float* __restrict__ W,
                                              float* __restrict__ H, int n) {
    constexpr int KP = K + 4;              // padded row stride (banks)
    __shared__ float Ws[K * HID];
    __shared__ float Xs[32 * KP];
    int tid = threadIdx.x;
    const float4* W4 = (const float4*)W;
    float4* Ws4 = (float4*)Ws;
    for (int i = tid; i < K * HID / 4; i += 256) Ws4[i] = W4[i];
    int row0 = blockIdx.x * 32;
    for (int i = tid; i < 32 * K / 4; i += 256) {
        int r  = i / (K / 4);
        int kv = i % (K / 4);
        float4 v = make_float4(0.f, 0.f, 0.f, 0.f);
        if (row0 + r < n) v = ((const float4*)(X + (size_t)(row0 + r) * K))[kv];
        ((float4*)(Xs + r * KP))[kv] = v;
    }
    __syncthreads();
    int cg = tid & 15;  int col0 = cg * 4;
    int rg = tid >> 4;  int r0 = rg * 2;
    float acc[2][4] = {};
    for (int k = 0; k < K; ++k) {
        float4 w = *(const float4*)(Ws + k * HID + col0);
        float x0 = Xs[r0 * KP + k];
        float x1 = Xs[(r0 + 1) * KP + k];
        acc[0][0] = fmaf(x0, w.x, acc[0][0]); acc[0][1] = fmaf(x0, w.y, acc[0][1]);
        acc[0][2] = fmaf(x0, w.z, acc[0][2]); acc[0][3] = fmaf(x0, w.w, acc[0][3]);
        acc[1][0] = fmaf(x1, w.x, acc[1][0]); acc[1][1] = fmaf(x1, w.y, acc[1][1]);
        acc[1][2] = fmaf(x1, w.z, acc[1][2]); acc[1][3] = fmaf(x1, w.w, acc[1][3]);
    }
    #pragma unroll
    for (int rr = 0; rr < 2; ++rr) {
        int row = row0 + r0 + rr;
        if (row < n)
            *(float4*)(H + (size_t)row * HID + col0) =
                make_float4(acc[rr][0], acc[rr][1], acc[rr][2], acc[rr][3]);
    }
}

// ---------------- gather-aggregate (fused bias + self-loop + edge sum) ----------------
__global__ __launch_bounds__(256) void k_agg(const int* __restrict__ off,
                                             const int* __restrict__ csr_src,
                                             const float* __restrict__ csr_c,
                                             const float* __restrict__ h,
                                             const float* __restrict__ dinv,
                                             const float* __restrict__ bias,
                                             const float* emb,
                                             float* __restrict__ out, int n) {
    int wid  = threadIdx.x >> 6;
    int lane = threadIdx.x & 63;
    int i = blockIdx.x * 4 + wid;
    if (i >= n) return;
    float di = dinv[i];
    float gself = sigmoidf_(emb[0]);       // sq = 0 on self-loop
    float acc = bias[lane] + gself * di * di * h[(size_t)i * HID + lane];
    int s = off[i], s1 = off[i + 1];
    for (; s + 4 <= s1; s += 4) {
        int r0 = csr_src[s], r1 = csr_src[s + 1], r2 = csr_src[s + 2], r3 = csr_src[s + 3];
        float c0 = csr_c[s], c1 = csr_c[s + 1], c2 = csr_c[s + 2], c3 = csr_c[s + 3];
        float v0 = h[(size_t)r0 * HID + lane];
        float v1 = h[(size_t)r1 * HID + lane];
        float v2 = h[(size_t)r2 * HID + lane];
        float v3 = h[(size_t)r3 * HID + lane];
        acc = fmaf(c0, v0, acc); acc = fmaf(c1, v1, acc);
        acc = fmaf(c2, v2, acc); acc = fmaf(c3, v3, acc);
    }
    for (; s < s1; ++s)
        acc = fmaf(csr_c[s], h[(size_t)csr_src[s] * HID + lane], acc);
    out[(size_t)i * HID + lane] = acc;
}

// ---------------- final link predictor ----------------
__global__ void k_predict(const int* __restrict__ pei, const int* __restrict__ nei,
                          const float* __restrict__ h, const float* __restrict__ pos,
                          const float* fcw, const float* fcb,
                          float* __restrict__ out, int Elp) {
    int sub  = threadIdx.x >> 6;
    int lane = threadIdx.x & 63;
    int e = blockIdx.x * 4 + sub;
    if (e >= 2 * Elp) return;
    int src, dst;
    if (e < Elp) { src = pei[e];        dst = pei[Elp + e]; }
    else         { src = nei[e - Elp];  dst = nei[e];       }
    float p = h[(size_t)src * HID + lane] * h[(size_t)dst * HID + lane];
    float pe = 0.0f;
    if (lane < 32) {
        float d = pos[(size_t)src * POS_DIM + lane] - pos[(size_t)dst * POS_DIM + lane];
        pe = d * d;
    }
    #pragma unroll
    for (int off = 32; off; off >>= 1) {
        p  += __shfl_down(p, off);
        pe += __shfl_down(pe, off);
    }
    if (lane == 0) out[e] = fcw[0] * p + fcw[1] * pe + fcb[0];
}

extern "C" void kernel_launch(void* const* d_in, const int* in_sizes, int n_in,
                              void* d_out, int out_size, void* d_ws, size_t ws_size,
                              hipStream_t stream) {
    const float* x    = (const float*)d_in[0];
    const float* pos  = (const float*)d_in[1];
    const int*   pei  = (const int*)d_in[2];
    const int*   nei  = (const int*)d_in[3];
    const int*   tp   = (const int*)d_in[4];
    const float* W1   = (const float*)d_in[5];
    const float* b1   = (const float*)d_in[6];
    const float* em1w = (const float*)d_in[7];
    const float* em1b = (const float*)d_in[8];
    const float* W2   = (const float*)d_in[9];
    const float* b2   = (const float*)d_in[10];
    const float* em2w = (const float*)d_in[11];
    const float* em2b = (const float*)d_in[12];
    const float* fcw  = (const float*)d_in[13];
    const float* fcb  = (const float*)d_in[14];
    float* outp = (float*)d_out;

    const int N   = in_sizes[0] / IN_DIM;   // 50000
    const int E   = in_sizes[4] / 2;        // 800000
    const int Elp = in_sizes[2] / 2;        // 100000

    char* ws = (char*)d_ws;
    int*   cur     = (int*)ws;                    ws += (size_t)N * 4;
    int*   off     = (int*)ws;                    ws += (size_t)(N + 1) * 4;
    float* dinv    = (float*)ws;                  ws += (size_t)N * 4;
    int*   csr_src = (int*)ws;                    ws += (size_t)E * 4;
    float* csr_c1  = (float*)ws;                  ws += (size_t)E * 4;
    float* csr_c2  = (float*)ws;                  ws += (size_t)E * 4;
    float* hbuf    = (float*)ws;                  ws += (size_t)N * HID * 4;
    float* obuf    = (float*)ws;                  ws += (size_t)N * HID * 4;

    // ---- CSR build ----
    hipMemsetAsync(cur, 0, (size_t)N * 4, stream);
    k_hist<<<(E + 255) / 256, 256, 0, stream>>>(tp, cur, E);
    k_dinv<<<(N + 255) / 256, 256, 0, stream>>>(cur, dinv, N);
    k_scan<<<1, 1024, 0, stream>>>(cur, off, N);
    k_coef_fill<<<(E + 7) / 8, 256, 0, stream>>>(tp, pos, dinv, em1w, em1b, em2w, em2b,
                                                 cur, csr_src, csr_c1, csr_c2, E);

    // ---- layer 1 ----
    k_gemm<IN_DIM><<<(N + 31) / 32, 256, 0, stream>>>(x, W1, hbuf, N);
    k_agg<<<(N + 3) / 4, 256, 0, stream>>>(off, csr_src, csr_c1, hbuf, dinv, b1, em1b, obuf, N);

    // ---- layer 2 ----
    k_gemm<HID><<<(N + 31) / 32, 256, 0, stream>>>(obuf, W2, hbuf, N);
    k_agg<<<(N + 3) / 4, 256, 0, stream>>>(off, csr_src, csr_c2, hbuf, dinv, b2, em2b, obuf, N);

    // ---- predictor ----
    k_predict<<<(2 * Elp + 3) / 4, 256, 0, stream>>>(pei, nei, obuf, pos, fcw, fcb, outp, Elp);
}

// Round 3
// 396.122 us; speedup vs baseline: 1.5302x; 1.0718x over previous
//
#include <hip/hip_runtime.h>

#define HID 64
#define POS_DIM 32
#define IN_DIM 128

__device__ __forceinline__ float fsig(float v) {
    return 1.0f / (1.0f + __expf(-v));
}

// ---------------- pass A: sqdist + rank + in-degree histogram ----------------
__global__ __launch_bounds__(256) void k_pre(const int* __restrict__ tp,
                                             const float* __restrict__ pos,
                                             int* cnt, float* __restrict__ sq,
                                             int* __restrict__ rank, int E) {
    int e = blockIdx.x * blockDim.x + threadIdx.x;
    if (e >= E) return;
    int row = tp[e];
    int col = tp[E + e];
    const float4* pr = (const float4*)(pos + (size_t)row * POS_DIM);
    const float4* pc = (const float4*)(pos + (size_t)col * POS_DIM);
    float acc = 0.0f;
    #pragma unroll
    for (int j = 0; j < POS_DIM / 4; ++j) {
        float4 a = pr[j], b = pc[j];
        float dx = a.x - b.x, dy = a.y - b.y, dz = a.z - b.z, dw = a.w - b.w;
        acc = fmaf(dx, dx, acc); acc = fmaf(dy, dy, acc);
        acc = fmaf(dz, dz, acc); acc = fmaf(dw, dw, acc);
    }
    sq[e] = acc;
    rank[e] = atomicAdd(&cnt[col], 1);
}

// ---------------- scan (exclusive) + dinv, single block ----------------
__global__ __launch_bounds__(1024) void k_scan(const int* __restrict__ cnt,
                                               int* __restrict__ off,
                                               float* __restrict__ dinv, int n) {
    __shared__ int sums[1024];
    int t = threadIdx.x;
    int ch = (n + 1023) / 1024;
    int lo = t * ch, hi = min(lo + ch, n);
    int s = 0;
    for (int i = lo; i < hi; ++i) {
        int c = cnt[i];
        dinv[i] = rsqrtf((float)(c + 1));   // +1 self-loop
        s += c;
    }
    sums[t] = s;
    __syncthreads();
    for (int d = 1; d < 1024; d <<= 1) {
        int v = 0;
        if (t >= d) v = sums[t - d];
        __syncthreads();
        if (t >= d) sums[t] += v;
        __syncthreads();
    }
    int run = sums[t] - s;   // exclusive prefix of this chunk
    for (int i = lo; i < hi; ++i) {
        off[i] = run;
        run += cnt[i];
    }
    if (t == 1023) off[n] = sums[1023];
}

// ---------------- pass B: CSR fill (no atomics) + coefs in edge order ----------------
__global__ __launch_bounds__(256) void k_fill(const int* __restrict__ tp,
                                              const int* __restrict__ off,
                                              const int* __restrict__ rank,
                                              const float* __restrict__ sq,
                                              const float* __restrict__ dinv,
                                              const float* em1w, const float* em1b,
                                              const float* em2w, const float* em2b,
                                              int2* __restrict__ csr_re,
                                              float* __restrict__ c1,
                                              float* __restrict__ c2, int E) {
    int e = blockIdx.x * blockDim.x + threadIdx.x;
    if (e >= E) return;
    int row = tp[e];
    int col = tp[E + e];
    int slot = off[col] + rank[e];
    csr_re[slot] = make_int2(row, e);
    float nrm = dinv[row] * dinv[col];
    float s = sq[e];
    c1[e] = fsig(s * em1w[0] + em1b[0]) * nrm;
    c2[e] = fsig(s * em2w[0] + em2b[0]) * nrm;
}

// ---------------- GEMM: H[n,64] = X[n,K] @ W[K,64], 32 rows/block ----------------
template<int K>
__global__ __launch_bounds__(256) void k_gemm(const float* __restrict__ X,
                                              const float* __restrict__ W,
                                              float* __restrict__ H, int n) {
    constexpr int KP = K + 4;
    __shared__ float Ws[K * HID];
    __shared__ float Xs[32 * KP];
    int tid = threadIdx.x;
    const float4* W4 = (const float4*)W;
    float4* Ws4 = (float4*)Ws;
    for (int i = tid; i < K * HID / 4; i += 256) Ws4[i] = W4[i];
    int row0 = blockIdx.x * 32;
    for (int i = tid; i < 32 * K / 4; i += 256) {
        int r  = i / (K / 4);
        int kv = i % (K / 4);
        float4 v = make_float4(0.f, 0.f, 0.f, 0.f);
        if (row0 + r < n) v = ((const float4*)(X + (size_t)(row0 + r) * K))[kv];
        ((float4*)(Xs + r * KP))[kv] = v;
    }
    __syncthreads();
    int cg = tid & 15;  int col0 = cg * 4;
    int rg = tid >> 4;  int r0 = rg * 2;
    float acc[2][4] = {};
    for (int k = 0; k < K; ++k) {
        float4 w = *(const float4*)(Ws + k * HID + col0);
        float x0 = Xs[r0 * KP + k];
        float x1 = Xs[(r0 + 1) * KP + k];
        acc[0][0] = fmaf(x0, w.x, acc[0][0]); acc[0][1] = fmaf(x0, w.y, acc[0][1]);
        acc[0][2] = fmaf(x0, w.z, acc[0][2]); acc[0][3] = fmaf(x0, w.w, acc[0][3]);
        acc[1][0] = fmaf(x1, w.x, acc[1][0]); acc[1][1] = fmaf(x1, w.y, acc[1][1]);
        acc[1][2] = fmaf(x1, w.z, acc[1][2]); acc[1][3] = fmaf(x1, w.w, acc[1][3]);
    }
    #pragma unroll
    for (int rr = 0; rr < 2; ++rr) {
        int row = row0 + r0 + rr;
        if (row < n)
            *(float4*)(H + (size_t)row * HID + col0) =
                make_float4(acc[rr][0], acc[rr][1], acc[rr][2], acc[rr][3]);
    }
}

// ---------------- gather-aggregate (bias + self-loop + edge sum) ----------------
__global__ __launch_bounds__(256) void k_agg(const int* __restrict__ off,
                                             const int2* __restrict__ csr_re,
                                             const float* __restrict__ cf,
                                             const float* __restrict__ h,
                                             const float* __restrict__ dinv,
                                             const float* __restrict__ bias,
                                             const float* emb,
                                             float* __restrict__ out, int n) {
    int wid  = threadIdx.x >> 6;
    int lane = threadIdx.x & 63;
    int i = blockIdx.x * 4 + wid;
    if (i >= n) return;
    float di = dinv[i];
    float gself = fsig(emb[0]);            // sq = 0 on self-loop
    float acc = bias[lane] + gself * di * di * h[(size_t)i * HID + lane];
    int s = off[i], s1 = off[i + 1];
    for (; s + 4 <= s1; s += 4) {
        int2 e0 = csr_re[s],     e1 = csr_re[s + 1];
        int2 e2 = csr_re[s + 2], e3 = csr_re[s + 3];
        float c0 = cf[e0.y], c1v = cf[e1.y], c2v = cf[e2.y], c3 = cf[e3.y];
        float v0 = h[(size_t)e0.x * HID + lane];
        float v1 = h[(size_t)e1.x * HID + lane];
        float v2 = h[(size_t)e2.x * HID + lane];
        float v3 = h[(size_t)e3.x * HID + lane];
        acc = fmaf(c0, v0, acc); acc = fmaf(c1v, v1, acc);
        acc = fmaf(c2v, v2, acc); acc = fmaf(c3, v3, acc);
    }
    for (; s < s1; ++s) {
        int2 e0 = csr_re[s];
        acc = fmaf(cf[e0.y], h[(size_t)e0.x * HID + lane], acc);
    }
    out[(size_t)i * HID + lane] = acc;
}

// ---------------- final link predictor ----------------
__global__ void k_predict(const int* __restrict__ pei, const int* __restrict__ nei,
                          const float* __restrict__ h, const float* __restrict__ pos,
                          const float* fcw, const float* fcb,
                          float* __restrict__ out, int Elp) {
    int sub  = threadIdx.x >> 6;
    int lane = threadIdx.x & 63;
    int e = blockIdx.x * 4 + sub;
    if (e >= 2 * Elp) return;
    int src, dst;
    if (e < Elp) { src = pei[e];        dst = pei[Elp + e]; }
    else         { src = nei[e - Elp];  dst = nei[e];       }
    float p = h[(size_t)src * HID + lane] * h[(size_t)dst * HID + lane];
    float pe = 0.0f;
    if (lane < 32) {
        float d = pos[(size_t)src * POS_DIM + lane] - pos[(size_t)dst * POS_DIM + lane];
        pe = d * d;
    }
    #pragma unroll
    for (int off = 32; off; off >>= 1) {
        p  += __shfl_down(p, off);
        pe += __shfl_down(pe, off);
    }
    if (lane == 0) out[e] = fcw[0] * p + fcw[1] * pe + fcb[0];
}

extern "C" void kernel_launch(void* const* d_in, const int* in_sizes, int n_in,
                              void* d_out, int out_size, void* d_ws, size_t ws_size,
                              hipStream_t stream) {
    const float* x    = (const float*)d_in[0];
    const float* pos  = (const float*)d_in[1];
    const int*   pei  = (const int*)d_in[2];
    const int*   nei  = (const int*)d_in[3];
    const int*   tp   = (const int*)d_in[4];
    const float* W1   = (const float*)d_in[5];
    const float* b1   = (const float*)d_in[6];
    const float* em1w = (const float*)d_in[7];
    const float* em1b = (const float*)d_in[8];
    const float* W2   = (const float*)d_in[9];
    const float* b2   = (const float*)d_in[10];
    const float* em2w = (const float*)d_in[11];
    const float* em2b = (const float*)d_in[12];
    const float* fcw  = (const float*)d_in[13];
    const float* fcb  = (const float*)d_in[14];
    float* outp = (float*)d_out;

    const int N   = in_sizes[0] / IN_DIM;   // 50000
    const int E   = in_sizes[4] / 2;        // 800000
    const int Elp = in_sizes[2] / 2;        // 100000

    char* p = (char*)d_ws;
    int*   cnt     = (int*)p;     p += (size_t)N * 4;
    int*   off     = (int*)p;     p += (size_t)(N + 1) * 4;
    float* dinv    = (float*)p;   p += (size_t)N * 4;
    float* c1      = (float*)p;   p += (size_t)E * 4;
    float* c2      = (float*)p;   p += (size_t)E * 4;
    int2*  csr_re  = (int2*)p;    p += (size_t)E * 8;
    float* obuf    = (float*)p;   p += (size_t)N * HID * 4;
    // rank/sq region aliased with hbuf (rank,sq dead before gemm1 writes hbuf)
    float* region  = (float*)p;   // max(2E, N*HID) floats
    int*   rank    = (int*)region;
    float* sq      = region + E;
    float* hbuf    = region;

    // ---- CSR build ----
    hipMemsetAsync(cnt, 0, (size_t)N * 4, stream);
    k_pre<<<(E + 255) / 256, 256, 0, stream>>>(tp, pos, cnt, sq, rank, E);
    k_scan<<<1, 1024, 0, stream>>>(cnt, off, dinv, N);
    k_fill<<<(E + 255) / 256, 256, 0, stream>>>(tp, off, rank, sq, dinv,
                                                em1w, em1b, em2w, em2b,
                                                csr_re, c1, c2, E);

    // ---- layer 1 ----
    k_gemm<IN_DIM><<<(N + 31) / 32, 256, 0, stream>>>(x, W1, hbuf, N);
    k_agg<<<(N + 3) / 4, 256, 0, stream>>>(off, csr_re, c1, hbuf, dinv, b1, em1b, obuf, N);

    // ---- layer 2 ----
    k_gemm<HID><<<(N + 31) / 32, 256, 0, stream>>>(obuf, W2, hbuf, N);
    k_agg<<<(N + 3) / 4, 256, 0, stream>>>(off, csr_re, c2, hbuf, dinv, b2, em2b, obuf, N);

    // ---- predictor ----
    k_predict<<<(2 * Elp + 3) / 4, 256, 0, stream>>>(pei, nei, obuf, pos, fcw, fcb, outp, Elp);
}

// Round 4
// 272.794 us; speedup vs baseline: 2.2220x; 1.4521x over previous
//
#include <hip/hip_runtime.h>

#define HID 64
#define POS_DIM 32
#define IN_DIM 128

__device__ __forceinline__ float fsig(float v) {
    return 1.0f / (1.0f + __expf(-v));
}

// ---------------- pass A: sqdist + rank + in-degree histogram ----------------
__global__ __launch_bounds__(256) void k_pre(const int* __restrict__ tp,
                                             const float* __restrict__ pos,
                                             int* cnt, float* __restrict__ sq,
                                             int* __restrict__ rank, int E) {
    int e = blockIdx.x * blockDim.x + threadIdx.x;
    if (e >= E) return;
    int row = tp[e];
    int col = tp[E + e];
    const float4* pr = (const float4*)(pos + (size_t)row * POS_DIM);
    const float4* pc = (const float4*)(pos + (size_t)col * POS_DIM);
    float acc = 0.0f;
    #pragma unroll
    for (int j = 0; j < POS_DIM / 4; ++j) {
        float4 a = pr[j], b = pc[j];
        float dx = a.x - b.x, dy = a.y - b.y, dz = a.z - b.z, dw = a.w - b.w;
        acc = fmaf(dx, dx, acc); acc = fmaf(dy, dy, acc);
        acc = fmaf(dz, dz, acc); acc = fmaf(dw, dw, acc);
    }
    sq[e] = acc;
    rank[e] = atomicAdd(&cnt[col], 1);
}

// ---------------- scan phase 1: per-block sums (256 elems/block) ----------------
__global__ __launch_bounds__(256) void k_bsum(const int* __restrict__ cnt,
                                              int* __restrict__ bsum, int n) {
    int i = blockIdx.x * 256 + threadIdx.x;
    int v = (i < n) ? cnt[i] : 0;
    #pragma unroll
    for (int o = 32; o; o >>= 1) v += __shfl_down(v, o);
    __shared__ int w[4];
    int lane = threadIdx.x & 63, wid = threadIdx.x >> 6;
    if (lane == 0) w[wid] = v;
    __syncthreads();
    if (threadIdx.x == 0) bsum[blockIdx.x] = w[0] + w[1] + w[2] + w[3];
}

// ---------------- scan phase 2: block prefix (redundant) + in-block scan + dinv ----------------
__global__ __launch_bounds__(256) void k_scan2(const int* __restrict__ cnt,
                                               const int* __restrict__ bsum,
                                               int* __restrict__ off,
                                               float* __restrict__ dinv,
                                               int n, int Etot) {
    __shared__ int s[256];
    __shared__ int wsum[4];
    int tid = threadIdx.x, bid = blockIdx.x;
    // exclusive block prefix: sum of bsum[0..bid)
    int p = 0;
    for (int t = tid; t < bid; t += 256) p += bsum[t];
    #pragma unroll
    for (int o = 32; o; o >>= 1) p += __shfl_down(p, o);
    int lane = tid & 63, wid = tid >> 6;
    if (lane == 0) wsum[wid] = p;
    __syncthreads();
    int bpre = wsum[0] + wsum[1] + wsum[2] + wsum[3];
    int i = bid * 256 + tid;
    int v = (i < n) ? cnt[i] : 0;
    s[tid] = v;
    __syncthreads();
    #pragma unroll
    for (int d = 1; d < 256; d <<= 1) {
        int t_ = (tid >= d) ? s[tid - d] : 0;
        __syncthreads();
        s[tid] += t_;
        __syncthreads();
    }
    if (i < n) {
        off[i]  = bpre + s[tid] - v;          // exclusive prefix
        dinv[i] = rsqrtf((float)(v + 1));     // +1 self-loop
    }
    if (i == 0) off[n] = Etot;
}

// ---------------- pass B: CSR fill (no atomics) + coefs in edge order ----------------
__global__ __launch_bounds__(256) void k_fill(const int* __restrict__ tp,
                                              const int* __restrict__ off,
                                              const int* __restrict__ rank,
                                              const float* __restrict__ sq,
                                              const float* __restrict__ dinv,
                                              const float* em1w, const float* em1b,
                                              const float* em2w, const float* em2b,
                                              int2* __restrict__ csr_re,
                                              float* __restrict__ c1,
                                              float* __restrict__ c2, int E) {
    int e = blockIdx.x * blockDim.x + threadIdx.x;
    if (e >= E) return;
    int row = tp[e];
    int col = tp[E + e];
    int slot = off[col] + rank[e];
    csr_re[slot] = make_int2(row, e);
    float nrm = dinv[row] * dinv[col];
    float s = sq[e];
    c1[e] = fsig(s * em1w[0] + em1b[0]) * nrm;
    c2[e] = fsig(s * em2w[0] + em2b[0]) * nrm;
}

// ---------------- GEMM: H[n,64] = X[n,K] @ W[K,64], 32 rows/block ----------------
template<int K>
__global__ __launch_bounds__(256) void k_gemm(const float* __restrict__ X,
                                              const float* __restrict__ W,
                                              float* __restrict__ H, int n) {
    constexpr int KP = K + 4;
    __shared__ float Ws[K * HID];
    __shared__ float Xs[32 * KP];
    int tid = threadIdx.x;
    const float4* W4 = (const float4*)W;
    float4* Ws4 = (float4*)Ws;
    for (int i = tid; i < K * HID / 4; i += 256) Ws4[i] = W4[i];
    int row0 = blockIdx.x * 32;
    for (int i = tid; i < 32 * K / 4; i += 256) {
        int r  = i / (K / 4);
        int kv = i % (K / 4);
        float4 v = make_float4(0.f, 0.f, 0.f, 0.f);
        if (row0 + r < n) v = ((const float4*)(X + (size_t)(row0 + r) * K))[kv];
        ((float4*)(Xs + r * KP))[kv] = v;
    }
    __syncthreads();
    int cg = tid & 15;  int col0 = cg * 4;
    int rg = tid >> 4;  int r0 = rg * 2;
    float acc[2][4] = {};
    for (int k = 0; k < K; ++k) {
        float4 w = *(const float4*)(Ws + k * HID + col0);
        float x0 = Xs[r0 * KP + k];
        float x1 = Xs[(r0 + 1) * KP + k];
        acc[0][0] = fmaf(x0, w.x, acc[0][0]); acc[0][1] = fmaf(x0, w.y, acc[0][1]);
        acc[0][2] = fmaf(x0, w.z, acc[0][2]); acc[0][3] = fmaf(x0, w.w, acc[0][3]);
        acc[1][0] = fmaf(x1, w.x, acc[1][0]); acc[1][1] = fmaf(x1, w.y, acc[1][1]);
        acc[1][2] = fmaf(x1, w.z, acc[1][2]); acc[1][3] = fmaf(x1, w.w, acc[1][3]);
    }
    #pragma unroll
    for (int rr = 0; rr < 2; ++rr) {
        int row = row0 + r0 + rr;
        if (row < n)
            *(float4*)(H + (size_t)row * HID + col0) =
                make_float4(acc[rr][0], acc[rr][1], acc[rr][2], acc[rr][3]);
    }
}

// ---------------- gather-aggregate (bias + self-loop + edge sum) ----------------
__global__ __launch_bounds__(256) void k_agg(const int* __restrict__ off,
                                             const int2* __restrict__ csr_re,
                                             const float* __restrict__ cf,
                                             const float* __restrict__ h,
                                             const float* __restrict__ dinv,
                                             const float* __restrict__ bias,
                                             const float* emb,
                                             float* __restrict__ out, int n) {
    int wid  = threadIdx.x >> 6;
    int lane = threadIdx.x & 63;
    int i = blockIdx.x * 4 + wid;
    if (i >= n) return;
    float di = dinv[i];
    float gself = fsig(emb[0]);            // sq = 0 on self-loop
    float acc = bias[lane] + gself * di * di * h[(size_t)i * HID + lane];
    int s = off[i], s1 = off[i + 1];
    for (; s + 4 <= s1; s += 4) {
        int2 e0 = csr_re[s],     e1 = csr_re[s + 1];
        int2 e2 = csr_re[s + 2], e3 = csr_re[s + 3];
        float c0 = cf[e0.y], c1v = cf[e1.y], c2v = cf[e2.y], c3 = cf[e3.y];
        float v0 = h[(size_t)e0.x * HID + lane];
        float v1 = h[(size_t)e1.x * HID + lane];
        float v2 = h[(size_t)e2.x * HID + lane];
        float v3 = h[(size_t)e3.x * HID + lane];
        acc = fmaf(c0, v0, acc); acc = fmaf(c1v, v1, acc);
        acc = fmaf(c2v, v2, acc); acc = fmaf(c3, v3, acc);
    }
    for (; s < s1; ++s) {
        int2 e0 = csr_re[s];
        acc = fmaf(cf[e0.y], h[(size_t)e0.x * HID + lane], acc);
    }
    out[(size_t)i * HID + lane] = acc;
}

// ---------------- final link predictor ----------------
__global__ void k_predict(const int* __restrict__ pei, const int* __restrict__ nei,
                          const float* __restrict__ h, const float* __restrict__ pos,
                          const float* fcw, const float* fcb,
                          float* __restrict__ out, int Elp) {
    int sub  = threadIdx.x >> 6;
    int lane = threadIdx.x & 63;
    int e = blockIdx.x * 4 + sub;
    if (e >= 2 * Elp) return;
    int src, dst;
    if (e < Elp) { src = pei[e];        dst = pei[Elp + e]; }
    else         { src = nei[e - Elp];  dst = nei[e];       }
    float p = h[(size_t)src * HID + lane] * h[(size_t)dst * HID + lane];
    float pe = 0.0f;
    if (lane < 32) {
        float d = pos[(size_t)src * POS_DIM + lane] - pos[(size_t)dst * POS_DIM + lane];
        pe = d * d;
    }
    #pragma unroll
    for (int off = 32; off; off >>= 1) {
        p  += __shfl_down(p, off);
        pe += __shfl_down(pe, off);
    }
    if (lane == 0) out[e] = fcw[0] * p + fcw[1] * pe + fcb[0];
}

extern "C" void kernel_launch(void* const* d_in, const int* in_sizes, int n_in,
                              void* d_out, int out_size, void* d_ws, size_t ws_size,
                              hipStream_t stream) {
    const float* x    = (const float*)d_in[0];
    const float* pos  = (const float*)d_in[1];
    const int*   pei  = (const int*)d_in[2];
    const int*   nei  = (const int*)d_in[3];
    const int*   tp   = (const int*)d_in[4];
    const float* W1   = (const float*)d_in[5];
    const float* b1   = (const float*)d_in[6];
    const float* em1w = (const float*)d_in[7];
    const float* em1b = (const float*)d_in[8];
    const float* W2   = (const float*)d_in[9];
    const float* b2   = (const float*)d_in[10];
    const float* em2w = (const float*)d_in[11];
    const float* em2b = (const float*)d_in[12];
    const float* fcw  = (const float*)d_in[13];
    const float* fcb  = (const float*)d_in[14];
    float* outp = (float*)d_out;

    const int N   = in_sizes[0] / IN_DIM;   // 50000
    const int E   = in_sizes[4] / 2;        // 800000
    const int Elp = in_sizes[2] / 2;        // 100000
    const int NB  = (N + 255) / 256;        // scan blocks

    char* p = (char*)d_ws;
    int*   cnt     = (int*)p;     p += (size_t)N * 4;
    int*   off     = (int*)p;     p += (size_t)(N + 1) * 4;
    int*   bsum    = (int*)p;     p += (size_t)NB * 4;
    float* dinv    = (float*)p;   p += (size_t)N * 4;
    float* c1      = (float*)p;   p += (size_t)E * 4;
    float* c2      = (float*)p;   p += (size_t)E * 4;
    int2*  csr_re  = (int2*)p;    p += (size_t)E * 8;
    float* obuf    = (float*)p;   p += (size_t)N * HID * 4;
    // rank/sq region aliased with hbuf (rank,sq dead before gemm1 writes hbuf)
    float* region  = (float*)p;   // max(2E, N*HID) floats
    int*   rank    = (int*)region;
    float* sq      = region + E;
    float* hbuf    = region;

    // ---- CSR build ----
    hipMemsetAsync(cnt, 0, (size_t)N * 4, stream);
    k_pre<<<(E + 255) / 256, 256, 0, stream>>>(tp, pos, cnt, sq, rank, E);
    k_bsum<<<NB, 256, 0, stream>>>(cnt, bsum, N);
    k_scan2<<<NB, 256, 0, stream>>>(cnt, bsum, off, dinv, N, E);
    k_fill<<<(E + 255) / 256, 256, 0, stream>>>(tp, off, rank, sq, dinv,
                                                em1w, em1b, em2w, em2b,
                                                csr_re, c1, c2, E);

    // ---- layer 1 ----
    k_gemm<IN_DIM><<<(N + 31) / 32, 256, 0, stream>>>(x, W1, hbuf, N);
    k_agg<<<(N + 3) / 4, 256, 0, stream>>>(off, csr_re, c1, hbuf, dinv, b1, em1b, obuf, N);

    // ---- layer 2 ----
    k_gemm<HID><<<(N + 31) / 32, 256, 0, stream>>>(obuf, W2, hbuf, N);
    k_agg<<<(N + 3) / 4, 256, 0, stream>>>(off, csr_re, c2, hbuf, dinv, b2, em2b, obuf, N);

    // ---- predictor ----
    k_predict<<<(2 * Elp + 3) / 4, 256, 0, stream>>>(pei, nei, obuf, pos, fcw, fcb, outp, Elp);
}

// Round 5
// 263.293 us; speedup vs baseline: 2.3022x; 1.0361x over previous
//
#include <hip/hip_runtime.h>

#define HID 64
#define POS_DIM 32
#define IN_DIM 128

__device__ __forceinline__ float fsig(float v) {
    return 1.0f / (1.0f + __expf(-v));
}

// ---------------- pass A: sqdist + rank + in-degree histogram ----------------
// 8 lanes per edge: lane j loads float4 #j of the 128-B pos row (coalesced).
__global__ __launch_bounds__(256) void k_pre(const int* __restrict__ tp,
                                             const float* __restrict__ pos,
                                             int* cnt, float* __restrict__ sq,
                                             int* __restrict__ rank, int E) {
    int lane = threadIdx.x & 63;
    int wid  = threadIdx.x >> 6;           // wave in block (0..3)
    int sub  = lane >> 3;                  // edge slot in wave (0..7)
    int j    = lane & 7;                   // float4 index in row (0..7)
    int e = (blockIdx.x * 4 + wid) * 8 + sub;
    if (e >= E) return;
    int row = tp[e];                       // broadcast across the 8-lane group
    int col = tp[E + e];
    float4 a = ((const float4*)(pos + (size_t)row * POS_DIM))[j];
    float4 b = ((const float4*)(pos + (size_t)col * POS_DIM))[j];
    float dx = a.x - b.x, dy = a.y - b.y, dz = a.z - b.z, dw = a.w - b.w;
    float s = 0.0f;
    s = fmaf(dx, dx, s); s = fmaf(dy, dy, s);
    s = fmaf(dz, dz, s); s = fmaf(dw, dw, s);
    s += __shfl_xor(s, 1);
    s += __shfl_xor(s, 2);
    s += __shfl_xor(s, 4);
    if (j == 0) {
        sq[e] = s;
        rank[e] = atomicAdd(&cnt[col], 1);
    }
}

// ---------------- scan phase 1: per-block sums (256 elems/block) ----------------
__global__ __launch_bounds__(256) void k_bsum(const int* __restrict__ cnt,
                                              int* __restrict__ bsum, int n) {
    int i = blockIdx.x * 256 + threadIdx.x;
    int v = (i < n) ? cnt[i] : 0;
    #pragma unroll
    for (int o = 32; o; o >>= 1) v += __shfl_down(v, o);
    __shared__ int w[4];
    int lane = threadIdx.x & 63, wid = threadIdx.x >> 6;
    if (lane == 0) w[wid] = v;
    __syncthreads();
    if (threadIdx.x == 0) bsum[blockIdx.x] = w[0] + w[1] + w[2] + w[3];
}

// ---------------- scan phase 2: block prefix (redundant) + in-block scan + dinv ----------------
__global__ __launch_bounds__(256) void k_scan2(const int* __restrict__ cnt,
                                               const int* __restrict__ bsum,
                                               int* __restrict__ off,
                                               float* __restrict__ dinv,
                                               int n, int Etot) {
    __shared__ int s[256];
    __shared__ int wsum[4];
    int tid = threadIdx.x, bid = blockIdx.x;
    int p = 0;
    for (int t = tid; t < bid; t += 256) p += bsum[t];
    #pragma unroll
    for (int o = 32; o; o >>= 1) p += __shfl_down(p, o);
    int lane = tid & 63, wid = tid >> 6;
    if (lane == 0) wsum[wid] = p;
    __syncthreads();
    int bpre = wsum[0] + wsum[1] + wsum[2] + wsum[3];
    int i = bid * 256 + tid;
    int v = (i < n) ? cnt[i] : 0;
    s[tid] = v;
    __syncthreads();
    #pragma unroll
    for (int d = 1; d < 256; d <<= 1) {
        int t_ = (tid >= d) ? s[tid - d] : 0;
        __syncthreads();
        s[tid] += t_;
        __syncthreads();
    }
    if (i < n) {
        off[i]  = bpre + s[tid] - v;
        dinv[i] = rsqrtf((float)(v + 1));
    }
    if (i == 0) off[n] = Etot;
}

// ---------------- pass B: CSR fill (no atomics) + coefs in edge order ----------------
__global__ __launch_bounds__(256) void k_fill(const int* __restrict__ tp,
                                              const int* __restrict__ off,
                                              const int* __restrict__ rank,
                                              const float* __restrict__ sq,
                                              const float* __restrict__ dinv,
                                              const float* em1w, const float* em1b,
                                              const float* em2w, const float* em2b,
                                              int2* __restrict__ csr_re,
                                              float* __restrict__ c1,
                                              float* __restrict__ c2, int E) {
    int e = blockIdx.x * blockDim.x + threadIdx.x;
    if (e >= E) return;
    int row = tp[e];
    int col = tp[E + e];
    int slot = off[col] + rank[e];
    csr_re[slot] = make_int2(row, e);
    float nrm = dinv[row] * dinv[col];
    float s = sq[e];
    c1[e] = fsig(s * em1w[0] + em1b[0]) * nrm;
    c2[e] = fsig(s * em2w[0] + em2b[0]) * nrm;
}

// ---------------- GEMM: H[n,64] = X[n,K] @ W[K,64], 32 rows/block ----------------
template<int K>
__global__ __launch_bounds__(256) void k_gemm(const float* __restrict__ X,
                                              const float* __restrict__ W,
                                              float* __restrict__ H, int n) {
    constexpr int KP = K + 4;
    __shared__ float Ws[K * HID];
    __shared__ float Xs[32 * KP];
    int tid = threadIdx.x;
    const float4* W4 = (const float4*)W;
    float4* Ws4 = (float4*)Ws;
    for (int i = tid; i < K * HID / 4; i += 256) Ws4[i] = W4[i];
    int row0 = blockIdx.x * 32;
    for (int i = tid; i < 32 * K / 4; i += 256) {
        int r  = i / (K / 4);
        int kv = i % (K / 4);
        float4 v = make_float4(0.f, 0.f, 0.f, 0.f);
        if (row0 + r < n) v = ((const float4*)(X + (size_t)(row0 + r) * K))[kv];
        ((float4*)(Xs + r * KP))[kv] = v;
    }
    __syncthreads();
    int cg = tid & 15;  int col0 = cg * 4;
    int rg = tid >> 4;  int r0 = rg * 2;
    float acc[2][4] = {};
    for (int k = 0; k < K; ++k) {
        float4 w = *(const float4*)(Ws + k * HID + col0);
        float x0 = Xs[r0 * KP + k];
        float x1 = Xs[(r0 + 1) * KP + k];
        acc[0][0] = fmaf(x0, w.x, acc[0][0]); acc[0][1] = fmaf(x0, w.y, acc[0][1]);
        acc[0][2] = fmaf(x0, w.z, acc[0][2]); acc[0][3] = fmaf(x0, w.w, acc[0][3]);
        acc[1][0] = fmaf(x1, w.x, acc[1][0]); acc[1][1] = fmaf(x1, w.y, acc[1][1]);
        acc[1][2] = fmaf(x1, w.z, acc[1][2]); acc[1][3] = fmaf(x1, w.w, acc[1][3]);
    }
    #pragma unroll
    for (int rr = 0; rr < 2; ++rr) {
        int row = row0 + r0 + rr;
        if (row < n)
            *(float4*)(H + (size_t)row * HID + col0) =
                make_float4(acc[rr][0], acc[rr][1], acc[rr][2], acc[rr][3]);
    }
}

// ---------------- gather-aggregate (bias + self-loop + edge sum) ----------------
__global__ __launch_bounds__(256) void k_agg(const int* __restrict__ off,
                                             const int2* __restrict__ csr_re,
                                             const float* __restrict__ cf,
                                             const float* __restrict__ h,
                                             const float* __restrict__ dinv,
                                             const float* __restrict__ bias,
                                             const float* emb,
                                             float* __restrict__ out, int n) {
    int wid  = threadIdx.x >> 6;
    int lane = threadIdx.x & 63;
    int i = blockIdx.x * 4 + wid;
    if (i >= n) return;
    float di = dinv[i];
    float gself = fsig(emb[0]);
    float acc = bias[lane] + gself * di * di * h[(size_t)i * HID + lane];
    int s = off[i], s1 = off[i + 1];
    for (; s + 4 <= s1; s += 4) {
        int2 e0 = csr_re[s],     e1 = csr_re[s + 1];
        int2 e2 = csr_re[s + 2], e3 = csr_re[s + 3];
        float c0 = cf[e0.y], c1v = cf[e1.y], c2v = cf[e2.y], c3 = cf[e3.y];
        float v0 = h[(size_t)e0.x * HID + lane];
        float v1 = h[(size_t)e1.x * HID + lane];
        float v2 = h[(size_t)e2.x * HID + lane];
        float v3 = h[(size_t)e3.x * HID + lane];
        acc = fmaf(c0, v0, acc); acc = fmaf(c1v, v1, acc);
        acc = fmaf(c2v, v2, acc); acc = fmaf(c3, v3, acc);
    }
    for (; s < s1; ++s) {
        int2 e0 = csr_re[s];
        acc = fmaf(cf[e0.y], h[(size_t)e0.x * HID + lane], acc);
    }
    out[(size_t)i * HID + lane] = acc;
}

// ---------------- final link predictor ----------------
__global__ void k_predict(const int* __restrict__ pei, const int* __restrict__ nei,
                          const float* __restrict__ h, const float* __restrict__ pos,
                          const float* fcw, const float* fcb,
                          float* __restrict__ out, int Elp) {
    int sub  = threadIdx.x >> 6;
    int lane = threadIdx.x & 63;
    int e = blockIdx.x * 4 + sub;
    if (e >= 2 * Elp) return;
    int src, dst;
    if (e < Elp) { src = pei[e];        dst = pei[Elp + e]; }
    else         { src = nei[e - Elp];  dst = nei[e];       }
    float p = h[(size_t)src * HID + lane] * h[(size_t)dst * HID + lane];
    float pe = 0.0f;
    if (lane < 32) {
        float d = pos[(size_t)src * POS_DIM + lane] - pos[(size_t)dst * POS_DIM + lane];
        pe = d * d;
    }
    #pragma unroll
    for (int off = 32; off; off >>= 1) {
        p  += __shfl_down(p, off);
        pe += __shfl_down(pe, off);
    }
    if (lane == 0) out[e] = fcw[0] * p + fcw[1] * pe + fcb[0];
}

extern "C" void kernel_launch(void* const* d_in, const int* in_sizes, int n_in,
                              void* d_out, int out_size, void* d_ws, size_t ws_size,
                              hipStream_t stream) {
    const float* x    = (const float*)d_in[0];
    const float* pos  = (const float*)d_in[1];
    const int*   pei  = (const int*)d_in[2];
    const int*   nei  = (const int*)d_in[3];
    const int*   tp   = (const int*)d_in[4];
    const float* W1   = (const float*)d_in[5];
    const float* b1   = (const float*)d_in[6];
    const float* em1w = (const float*)d_in[7];
    const float* em1b = (const float*)d_in[8];
    const float* W2   = (const float*)d_in[9];
    const float* b2   = (const float*)d_in[10];
    const float* em2w = (const float*)d_in[11];
    const float* em2b = (const float*)d_in[12];
    const float* fcw  = (const float*)d_in[13];
    const float* fcb  = (const float*)d_in[14];
    float* outp = (float*)d_out;

    const int N   = in_sizes[0] / IN_DIM;   // 50000
    const int E   = in_sizes[4] / 2;        // 800000
    const int Elp = in_sizes[2] / 2;        // 100000
    const int NB  = (N + 255) / 256;        // scan blocks

    char* p = (char*)d_ws;
    int*   cnt     = (int*)p;     p += (size_t)N * 4;
    int*   off     = (int*)p;     p += (size_t)(N + 1) * 4;
    int*   bsum    = (int*)p;     p += (size_t)NB * 4;
    float* dinv    = (float*)p;   p += (size_t)N * 4;
    float* c1      = (float*)p;   p += (size_t)E * 4;
    float* c2      = (float*)p;   p += (size_t)E * 4;
    int2*  csr_re  = (int2*)p;    p += (size_t)E * 8;
    float* obuf    = (float*)p;   p += (size_t)N * HID * 4;
    float* region  = (float*)p;   // max(2E, N*HID) floats; rank/sq alias hbuf
    int*   rank    = (int*)region;
    float* sq      = region + E;
    float* hbuf    = region;

    // ---- CSR build ----
    hipMemsetAsync(cnt, 0, (size_t)N * 4, stream);
    k_pre<<<(E + 31) / 32, 256, 0, stream>>>(tp, pos, cnt, sq, rank, E);
    k_bsum<<<NB, 256, 0, stream>>>(cnt, bsum, N);
    k_scan2<<<NB, 256, 0, stream>>>(cnt, bsum, off, dinv, N, E);
    k_fill<<<(E + 255) / 256, 256, 0, stream>>>(tp, off, rank, sq, dinv,
                                                em1w, em1b, em2w, em2b,
                                                csr_re, c1, c2, E);

    // ---- layer 1 ----
    k_gemm<IN_DIM><<<(N + 31) / 32, 256, 0, stream>>>(x, W1, hbuf, N);
    k_agg<<<(N + 3) / 4, 256, 0, stream>>>(off, csr_re, c1, hbuf, dinv, b1, em1b, obuf, N);

    // ---- layer 2 ----
    k_gemm<HID><<<(N + 31) / 32, 256, 0, stream>>>(obuf, W2, hbuf, N);
    k_agg<<<(N + 3) / 4, 256, 0, stream>>>(off, csr_re, c2, hbuf, dinv, b2, em2b, obuf, N);

    // ---- predictor ----
    k_predict<<<(2 * Elp + 3) / 4, 256, 0, stream>>>(pei, nei, obuf, pos, fcw, fcb, outp, Elp);
}

// Round 6
// 242.669 us; speedup vs baseline: 2.4978x; 1.0850x over previous
//
#include <hip/hip_runtime.h>

#define HID 64
#define POS_DIM 32
#define IN_DIM 128

__device__ __forceinline__ float fsig(float v) {
    return 1.0f / (1.0f + __expf(-v));
}

// round-to-nearest-even fp32 -> bf16 bits
__device__ __forceinline__ unsigned short f2bf(float f) {
    unsigned int u = __float_as_uint(f);
    u = u + 0x7FFFu + ((u >> 16) & 1u);
    return (unsigned short)(u >> 16);
}
__device__ __forceinline__ float bf2f(unsigned short s) {
    return __uint_as_float(((unsigned int)s) << 16);
}

// ---------------- pass A: sqdist + rank + in-degree histogram ----------------
// 8 lanes per edge: lane j loads float4 #j of the 128-B pos row (coalesced).
__global__ __launch_bounds__(256) void k_pre(const int* __restrict__ tp,
                                             const float* __restrict__ pos,
                                             int* cnt, float* __restrict__ sq,
                                             int* __restrict__ rank, int E) {
    int lane = threadIdx.x & 63;
    int wid  = threadIdx.x >> 6;
    int sub  = lane >> 3;
    int j    = lane & 7;
    int e = (blockIdx.x * 4 + wid) * 8 + sub;
    if (e >= E) return;
    int row = tp[e];
    int col = tp[E + e];
    float4 a = ((const float4*)(pos + (size_t)row * POS_DIM))[j];
    float4 b = ((const float4*)(pos + (size_t)col * POS_DIM))[j];
    float dx = a.x - b.x, dy = a.y - b.y, dz = a.z - b.z, dw = a.w - b.w;
    float s = 0.0f;
    s = fmaf(dx, dx, s); s = fmaf(dy, dy, s);
    s = fmaf(dz, dz, s); s = fmaf(dw, dw, s);
    s += __shfl_xor(s, 1);
    s += __shfl_xor(s, 2);
    s += __shfl_xor(s, 4);
    if (j == 0) {
        sq[e] = s;
        rank[e] = atomicAdd(&cnt[col], 1);
    }
}

// ---------------- scan phase 1: per-block sums ----------------
__global__ __launch_bounds__(256) void k_bsum(const int* __restrict__ cnt,
                                              int* __restrict__ bsum, int n) {
    int i = blockIdx.x * 256 + threadIdx.x;
    int v = (i < n) ? cnt[i] : 0;
    #pragma unroll
    for (int o = 32; o; o >>= 1) v += __shfl_down(v, o);
    __shared__ int w[4];
    int lane = threadIdx.x & 63, wid = threadIdx.x >> 6;
    if (lane == 0) w[wid] = v;
    __syncthreads();
    if (threadIdx.x == 0) bsum[blockIdx.x] = w[0] + w[1] + w[2] + w[3];
}

// ---------------- scan phase 2 ----------------
__global__ __launch_bounds__(256) void k_scan2(const int* __restrict__ cnt,
                                               const int* __restrict__ bsum,
                                               int* __restrict__ off,
                                               float* __restrict__ dinv,
                                               int n, int Etot) {
    __shared__ int s[256];
    __shared__ int wsum[4];
    int tid = threadIdx.x, bid = blockIdx.x;
    int p = 0;
    for (int t = tid; t < bid; t += 256) p += bsum[t];
    #pragma unroll
    for (int o = 32; o; o >>= 1) p += __shfl_down(p, o);
    int lane = tid & 63, wid = tid >> 6;
    if (lane == 0) wsum[wid] = p;
    __syncthreads();
    int bpre = wsum[0] + wsum[1] + wsum[2] + wsum[3];
    int i = bid * 256 + tid;
    int v = (i < n) ? cnt[i] : 0;
    s[tid] = v;
    __syncthreads();
    #pragma unroll
    for (int d = 1; d < 256; d <<= 1) {
        int t_ = (tid >= d) ? s[tid - d] : 0;
        __syncthreads();
        s[tid] += t_;
        __syncthreads();
    }
    if (i < n) {
        off[i]  = bpre + s[tid] - v;
        dinv[i] = rsqrtf((float)(v + 1));
    }
    if (i == 0) off[n] = Etot;
}

// ---------------- pass B: CSR fill — int4{row, c1bits, c2bits, 0} ----------------
__global__ __launch_bounds__(256) void k_fill(const int* __restrict__ tp,
                                              const int* __restrict__ off,
                                              const int* __restrict__ rank,
                                              const float* __restrict__ sq,
                                              const float* __restrict__ dinv,
                                              const float* em1w, const float* em1b,
                                              const float* em2w, const float* em2b,
                                              int4* __restrict__ csr, int E) {
    int e = blockIdx.x * blockDim.x + threadIdx.x;
    if (e >= E) return;
    int row = tp[e];
    int col = tp[E + e];
    int slot = off[col] + rank[e];
    float nrm = dinv[row] * dinv[col];
    float s = sq[e];
    float c1 = fsig(s * em1w[0] + em1b[0]) * nrm;
    float c2 = fsig(s * em2w[0] + em2b[0]) * nrm;
    csr[slot] = make_int4(row, __float_as_int(c1), __float_as_int(c2), 0);
}

// ---------------- GEMM: H[n,64] = X[n,K] @ W[K,64], fp32 in, bf16 out ----------------
template<int K>
__global__ __launch_bounds__(256) void k_gemm(const float* __restrict__ X,
                                              const float* __restrict__ W,
                                              unsigned short* __restrict__ H, int n) {
    constexpr int KP = K + 4;
    __shared__ float Ws[K * HID];
    __shared__ float Xs[32 * KP];
    int tid = threadIdx.x;
    const float4* W4 = (const float4*)W;
    float4* Ws4 = (float4*)Ws;
    for (int i = tid; i < K * HID / 4; i += 256) Ws4[i] = W4[i];
    int row0 = blockIdx.x * 32;
    for (int i = tid; i < 32 * K / 4; i += 256) {
        int r  = i / (K / 4);
        int kv = i % (K / 4);
        float4 v = make_float4(0.f, 0.f, 0.f, 0.f);
        if (row0 + r < n) v = ((const float4*)(X + (size_t)(row0 + r) * K))[kv];
        ((float4*)(Xs + r * KP))[kv] = v;
    }
    __syncthreads();
    int cg = tid & 15;  int col0 = cg * 4;
    int rg = tid >> 4;  int r0 = rg * 2;
    float acc[2][4] = {};
    for (int k = 0; k < K; ++k) {
        float4 w = *(const float4*)(Ws + k * HID + col0);
        float x0 = Xs[r0 * KP + k];
        float x1 = Xs[(r0 + 1) * KP + k];
        acc[0][0] = fmaf(x0, w.x, acc[0][0]); acc[0][1] = fmaf(x0, w.y, acc[0][1]);
        acc[0][2] = fmaf(x0, w.z, acc[0][2]); acc[0][3] = fmaf(x0, w.w, acc[0][3]);
        acc[1][0] = fmaf(x1, w.x, acc[1][0]); acc[1][1] = fmaf(x1, w.y, acc[1][1]);
        acc[1][2] = fmaf(x1, w.z, acc[1][2]); acc[1][3] = fmaf(x1, w.w, acc[1][3]);
    }
    #pragma unroll
    for (int rr = 0; rr < 2; ++rr) {
        int row = row0 + r0 + rr;
        if (row < n) {
            ushort4 o;
            o.x = f2bf(acc[rr][0]); o.y = f2bf(acc[rr][1]);
            o.z = f2bf(acc[rr][2]); o.w = f2bf(acc[rr][3]);
            *(ushort4*)(H + (size_t)row * HID + col0) = o;
        }
    }
}

// ---------------- gather-aggregate (bias + self-loop + edge sum), bf16 h ----------------
__global__ __launch_bounds__(256) void k_agg(const int* __restrict__ off,
                                             const int4* __restrict__ csr,
                                             const unsigned short* __restrict__ h,
                                             const float* __restrict__ dinv,
                                             const float* __restrict__ bias,
                                             const float* emb,
                                             float* __restrict__ out, int n,
                                             int layer) {
    int wid  = threadIdx.x >> 6;
    int lane = threadIdx.x & 63;
    int i = blockIdx.x * 4 + wid;
    if (i >= n) return;
    float di = dinv[i];
    float gself = fsig(emb[0]);
    float acc = bias[lane] + gself * di * di * bf2f(h[(size_t)i * HID + lane]);
    int s = off[i], s1 = off[i + 1];
    for (; s + 4 <= s1; s += 4) {
        int4 e0 = csr[s],     e1 = csr[s + 1];
        int4 e2 = csr[s + 2], e3 = csr[s + 3];
        float c0 = __int_as_float(layer ? e0.z : e0.y);
        float c1 = __int_as_float(layer ? e1.z : e1.y);
        float c2 = __int_as_float(layer ? e2.z : e2.y);
        float c3 = __int_as_float(layer ? e3.z : e3.y);
        float v0 = bf2f(h[(size_t)e0.x * HID + lane]);
        float v1 = bf2f(h[(size_t)e1.x * HID + lane]);
        float v2 = bf2f(h[(size_t)e2.x * HID + lane]);
        float v3 = bf2f(h[(size_t)e3.x * HID + lane]);
        acc = fmaf(c0, v0, acc); acc = fmaf(c1, v1, acc);
        acc = fmaf(c2, v2, acc); acc = fmaf(c3, v3, acc);
    }
    for (; s < s1; ++s) {
        int4 e0 = csr[s];
        acc = fmaf(__int_as_float(layer ? e0.z : e0.y),
                   bf2f(h[(size_t)e0.x * HID + lane]), acc);
    }
    out[(size_t)i * HID + lane] = acc;
}

// ---------------- final link predictor ----------------
__global__ void k_predict(const int* __restrict__ pei, const int* __restrict__ nei,
                          const float* __restrict__ h, const float* __restrict__ pos,
                          const float* fcw, const float* fcb,
                          float* __restrict__ out, int Elp) {
    int sub  = threadIdx.x >> 6;
    int lane = threadIdx.x & 63;
    int e = blockIdx.x * 4 + sub;
    if (e >= 2 * Elp) return;
    int src, dst;
    if (e < Elp) { src = pei[e];        dst = pei[Elp + e]; }
    else         { src = nei[e - Elp];  dst = nei[e];       }
    float p = h[(size_t)src * HID + lane] * h[(size_t)dst * HID + lane];
    float pe = 0.0f;
    if (lane < 32) {
        float d = pos[(size_t)src * POS_DIM + lane] - pos[(size_t)dst * POS_DIM + lane];
        pe = d * d;
    }
    #pragma unroll
    for (int off = 32; off; off >>= 1) {
        p  += __shfl_down(p, off);
        pe += __shfl_down(pe, off);
    }
    if (lane == 0) out[e] = fcw[0] * p + fcw[1] * pe + fcb[0];
}

static inline size_t align16(size_t v) { return (v + 15) & ~(size_t)15; }

extern "C" void kernel_launch(void* const* d_in, const int* in_sizes, int n_in,
                              void* d_out, int out_size, void* d_ws, size_t ws_size,
                              hipStream_t stream) {
    const float* x    = (const float*)d_in[0];
    const float* pos  = (const float*)d_in[1];
    const int*   pei  = (const int*)d_in[2];
    const int*   nei  = (const int*)d_in[3];
    const int*   tp   = (const int*)d_in[4];
    const float* W1   = (const float*)d_in[5];
    const float* b1   = (const float*)d_in[6];
    const float* em1w = (const float*)d_in[7];
    const float* em1b = (const float*)d_in[8];
    const float* W2   = (const float*)d_in[9];
    const float* b2   = (const float*)d_in[10];
    const float* em2w = (const float*)d_in[11];
    const float* em2b = (const float*)d_in[12];
    const float* fcw  = (const float*)d_in[13];
    const float* fcb  = (const float*)d_in[14];
    float* outp = (float*)d_out;

    const int N   = in_sizes[0] / IN_DIM;   // 50000
    const int E   = in_sizes[4] / 2;        // 800000
    const int Elp = in_sizes[2] / 2;        // 100000
    const int NB  = (N + 255) / 256;

    char* base = (char*)d_ws;
    size_t o = 0;
    int4* csr = (int4*)(base + o);          o += align16((size_t)E * 16);
    int*   cnt  = (int*)(base + o);         o += align16((size_t)N * 4);
    int*   off  = (int*)(base + o);         o += align16((size_t)(N + 1) * 4);
    int*   bsum = (int*)(base + o);         o += align16((size_t)NB * 4);
    float* dinv = (float*)(base + o);       o += align16((size_t)N * 4);
    float* obuf = (float*)(base + o);       o += align16((size_t)N * HID * 4);
    // rank/sq (2E ints/floats) alias hbuf (N*HID ushort) — rank,sq dead before gemm1
    char*  region = base + o;
    int*   rank = (int*)region;
    float* sq   = (float*)(region + align16((size_t)E * 4));
    unsigned short* hbuf = (unsigned short*)region;

    // ---- CSR build ----
    hipMemsetAsync(cnt, 0, (size_t)N * 4, stream);
    k_pre<<<(E + 31) / 32, 256, 0, stream>>>(tp, pos, cnt, sq, rank, E);
    k_bsum<<<NB, 256, 0, stream>>>(cnt, bsum, N);
    k_scan2<<<NB, 256, 0, stream>>>(cnt, bsum, off, dinv, N, E);
    k_fill<<<(E + 255) / 256, 256, 0, stream>>>(tp, off, rank, sq, dinv,
                                                em1w, em1b, em2w, em2b, csr, E);

    // ---- layer 1 ----
    k_gemm<IN_DIM><<<(N + 31) / 32, 256, 0, stream>>>(x, W1, hbuf, N);
    k_agg<<<(N + 3) / 4, 256, 0, stream>>>(off, csr, hbuf, dinv, b1, em1b, obuf, N, 0);

    // ---- layer 2 ----
    k_gemm<HID><<<(N + 31) / 32, 256, 0, stream>>>(obuf, W2, hbuf, N);
    k_agg<<<(N + 3) / 4, 256, 0, stream>>>(off, csr, hbuf, dinv, b2, em2b, obuf, N, 1);

    // ---- predictor ----
    k_predict<<<(2 * Elp + 3) / 4, 256, 0, stream>>>(pei, nei, obuf, pos, fcw, fcb, outp, Elp);
}

// Round 7
// 217.972 us; speedup vs baseline: 2.7808x; 1.1133x over previous
//
#include <hip/hip_runtime.h>

#define HID 64
#define POS_DIM 32
#define IN_DIM 128

__device__ __forceinline__ float fsig(float v) {
    return 1.0f / (1.0f + __expf(-v));
}

// round-to-nearest-even fp32 -> bf16 bits
__device__ __forceinline__ unsigned short f2bf(float f) {
    unsigned int u = __float_as_uint(f);
    u = u + 0x7FFFu + ((u >> 16) & 1u);
    return (unsigned short)(u >> 16);
}
__device__ __forceinline__ float bf2f(unsigned short s) {
    return __uint_as_float(((unsigned int)s) << 16);
}
__device__ __forceinline__ float2 bfpair(unsigned int u) {
    return make_float2(__uint_as_float(u << 16),
                       __uint_as_float(u & 0xFFFF0000u));
}

// ---------------- pass A: sqdist + rank + in-degree histogram ----------------
// 8 lanes per edge: lane j loads float4 #j of the 128-B pos row (coalesced).
__global__ __launch_bounds__(256) void k_pre(const int* __restrict__ tp,
                                             const float* __restrict__ pos,
                                             int* cnt, float* __restrict__ sq,
                                             int* __restrict__ rank, int E) {
    int lane = threadIdx.x & 63;
    int wid  = threadIdx.x >> 6;
    int sub  = lane >> 3;
    int j    = lane & 7;
    int e = (blockIdx.x * 4 + wid) * 8 + sub;
    if (e >= E) return;
    int row = tp[e];
    int col = tp[E + e];
    float4 a = ((const float4*)(pos + (size_t)row * POS_DIM))[j];
    float4 b = ((const float4*)(pos + (size_t)col * POS_DIM))[j];
    float dx = a.x - b.x, dy = a.y - b.y, dz = a.z - b.z, dw = a.w - b.w;
    float s = 0.0f;
    s = fmaf(dx, dx, s); s = fmaf(dy, dy, s);
    s = fmaf(dz, dz, s); s = fmaf(dw, dw, s);
    s += __shfl_xor(s, 1);
    s += __shfl_xor(s, 2);
    s += __shfl_xor(s, 4);
    if (j == 0) {
        sq[e] = s;
        rank[e] = atomicAdd(&cnt[col], 1);
    }
}

// ---------------- scan phase 1: per-block sums ----------------
__global__ __launch_bounds__(256) void k_bsum(const int* __restrict__ cnt,
                                              int* __restrict__ bsum, int n) {
    int i = blockIdx.x * 256 + threadIdx.x;
    int v = (i < n) ? cnt[i] : 0;
    #pragma unroll
    for (int o = 32; o; o >>= 1) v += __shfl_down(v, o);
    __shared__ int w[4];
    int lane = threadIdx.x & 63, wid = threadIdx.x >> 6;
    if (lane == 0) w[wid] = v;
    __syncthreads();
    if (threadIdx.x == 0) bsum[blockIdx.x] = w[0] + w[1] + w[2] + w[3];
}

// ---------------- scan phase 2 ----------------
__global__ __launch_bounds__(256) void k_scan2(const int* __restrict__ cnt,
                                               const int* __restrict__ bsum,
                                               int* __restrict__ off,
                                               float* __restrict__ dinv,
                                               int n, int Etot) {
    __shared__ int s[256];
    __shared__ int wsum[4];
    int tid = threadIdx.x, bid = blockIdx.x;
    int p = 0;
    for (int t = tid; t < bid; t += 256) p += bsum[t];
    #pragma unroll
    for (int o = 32; o; o >>= 1) p += __shfl_down(p, o);
    int lane = tid & 63, wid = tid >> 6;
    if (lane == 0) wsum[wid] = p;
    __syncthreads();
    int bpre = wsum[0] + wsum[1] + wsum[2] + wsum[3];
    int i = bid * 256 + tid;
    int v = (i < n) ? cnt[i] : 0;
    s[tid] = v;
    __syncthreads();
    #pragma unroll
    for (int d = 1; d < 256; d <<= 1) {
        int t_ = (tid >= d) ? s[tid - d] : 0;
        __syncthreads();
        s[tid] += t_;
        __syncthreads();
    }
    if (i < n) {
        off[i]  = bpre + s[tid] - v;
        dinv[i] = rsqrtf((float)(v + 1));
    }
    if (i == 0) off[n] = Etot;
}

// ---------------- pass B: CSR fill — int4{row, c1bits, c2bits, 0} ----------------
__global__ __launch_bounds__(256) void k_fill(const int* __restrict__ tp,
                                              const int* __restrict__ off,
                                              const int* __restrict__ rank,
                                              const float* __restrict__ sq,
                                              const float* __restrict__ dinv,
                                              const float* em1w, const float* em1b,
                                              const float* em2w, const float* em2b,
                                              int4* __restrict__ csr, int E) {
    int e = blockIdx.x * blockDim.x + threadIdx.x;
    if (e >= E) return;
    int row = tp[e];
    int col = tp[E + e];
    int slot = off[col] + rank[e];
    float nrm = dinv[row] * dinv[col];
    float s = sq[e];
    float c1 = fsig(s * em1w[0] + em1b[0]) * nrm;
    float c2 = fsig(s * em2w[0] + em2b[0]) * nrm;
    csr[slot] = make_int4(row, __float_as_int(c1), __float_as_int(c2), 0);
}

// ---------------- GEMM: H[n,64] = X[n,K] @ W[K,64], fp32 in, bf16 out ----------------
template<int K>
__global__ __launch_bounds__(256) void k_gemm(const float* __restrict__ X,
                                              const float* __restrict__ W,
                                              unsigned short* __restrict__ H, int n) {
    constexpr int KP = K + 4;
    __shared__ float Ws[K * HID];
    __shared__ float Xs[32 * KP];
    int tid = threadIdx.x;
    const float4* W4 = (const float4*)W;
    float4* Ws4 = (float4*)Ws;
    for (int i = tid; i < K * HID / 4; i += 256) Ws4[i] = W4[i];
    int row0 = blockIdx.x * 32;
    for (int i = tid; i < 32 * K / 4; i += 256) {
        int r  = i / (K / 4);
        int kv = i % (K / 4);
        float4 v = make_float4(0.f, 0.f, 0.f, 0.f);
        if (row0 + r < n) v = ((const float4*)(X + (size_t)(row0 + r) * K))[kv];
        ((float4*)(Xs + r * KP))[kv] = v;
    }
    __syncthreads();
    int cg = tid & 15;  int col0 = cg * 4;
    int rg = tid >> 4;  int r0 = rg * 2;
    float acc[2][4] = {};
    for (int k = 0; k < K; ++k) {
        float4 w = *(const float4*)(Ws + k * HID + col0);
        float x0 = Xs[r0 * KP + k];
        float x1 = Xs[(r0 + 1) * KP + k];
        acc[0][0] = fmaf(x0, w.x, acc[0][0]); acc[0][1] = fmaf(x0, w.y, acc[0][1]);
        acc[0][2] = fmaf(x0, w.z, acc[0][2]); acc[0][3] = fmaf(x0, w.w, acc[0][3]);
        acc[1][0] = fmaf(x1, w.x, acc[1][0]); acc[1][1] = fmaf(x1, w.y, acc[1][1]);
        acc[1][2] = fmaf(x1, w.z, acc[1][2]); acc[1][3] = fmaf(x1, w.w, acc[1][3]);
    }
    #pragma unroll
    for (int rr = 0; rr < 2; ++rr) {
        int row = row0 + r0 + rr;
        if (row < n) {
            ushort4 o;
            o.x = f2bf(acc[rr][0]); o.y = f2bf(acc[rr][1]);
            o.z = f2bf(acc[rr][2]); o.w = f2bf(acc[rr][3]);
            *(ushort4*)(H + (size_t)row * HID + col0) = o;
        }
    }
}

// ---------------- gather-aggregate (bias + self-loop + edge sum), bf16 h ----------------
template<bool BF16OUT>
__global__ __launch_bounds__(256) void k_agg(const int* __restrict__ off,
                                             const int4* __restrict__ csr,
                                             const unsigned short* __restrict__ h,
                                             const float* __restrict__ dinv,
                                             const float* __restrict__ bias,
                                             const float* emb,
                                             void* __restrict__ outv, int n,
                                             int layer) {
    int wid  = threadIdx.x >> 6;
    int lane = threadIdx.x & 63;
    int i = blockIdx.x * 4 + wid;
    if (i >= n) return;
    float di = dinv[i];
    float gself = fsig(emb[0]);
    float acc = bias[lane] + gself * di * di * bf2f(h[(size_t)i * HID + lane]);
    int s = off[i], s1 = off[i + 1];
    for (; s + 4 <= s1; s += 4) {
        int4 e0 = csr[s],     e1 = csr[s + 1];
        int4 e2 = csr[s + 2], e3 = csr[s + 3];
        float c0 = __int_as_float(layer ? e0.z : e0.y);
        float c1 = __int_as_float(layer ? e1.z : e1.y);
        float c2 = __int_as_float(layer ? e2.z : e2.y);
        float c3 = __int_as_float(layer ? e3.z : e3.y);
        float v0 = bf2f(h[(size_t)e0.x * HID + lane]);
        float v1 = bf2f(h[(size_t)e1.x * HID + lane]);
        float v2 = bf2f(h[(size_t)e2.x * HID + lane]);
        float v3 = bf2f(h[(size_t)e3.x * HID + lane]);
        acc = fmaf(c0, v0, acc); acc = fmaf(c1, v1, acc);
        acc = fmaf(c2, v2, acc); acc = fmaf(c3, v3, acc);
    }
    for (; s < s1; ++s) {
        int4 e0 = csr[s];
        acc = fmaf(__int_as_float(layer ? e0.z : e0.y),
                   bf2f(h[(size_t)e0.x * HID + lane]), acc);
    }
    if (BF16OUT) ((unsigned short*)outv)[(size_t)i * HID + lane] = f2bf(acc);
    else         ((float*)outv)[(size_t)i * HID + lane] = acc;
}

// ---------------- final link predictor: 8 lanes per edge, bf16 h ----------------
__global__ __launch_bounds__(256) void k_predict(const int* __restrict__ pei,
                                                 const int* __restrict__ nei,
                                                 const unsigned short* __restrict__ h,
                                                 const float* __restrict__ pos,
                                                 const float* fcw, const float* fcb,
                                                 float* __restrict__ out, int Elp) {
    int j = threadIdx.x & 7;               // chunk index within rows
    int e = blockIdx.x * 32 + (threadIdx.x >> 3);
    if (e >= 2 * Elp) return;
    int src, dst;
    if (e < Elp) { src = pei[e];        dst = pei[Elp + e]; }
    else         { src = nei[e - Elp];  dst = nei[e];       }
    // h rows: 64 bf16 = 128 B; lane j takes uint4 #j (8 values)
    uint4 hs = ((const uint4*)(h + (size_t)src * HID))[j];
    uint4 hd = ((const uint4*)(h + (size_t)dst * HID))[j];
    float p = 0.0f;
    {
        float2 a, b;
        a = bfpair(hs.x); b = bfpair(hd.x);
        p = fmaf(a.x, b.x, p); p = fmaf(a.y, b.y, p);
        a = bfpair(hs.y); b = bfpair(hd.y);
        p = fmaf(a.x, b.x, p); p = fmaf(a.y, b.y, p);
        a = bfpair(hs.z); b = bfpair(hd.z);
        p = fmaf(a.x, b.x, p); p = fmaf(a.y, b.y, p);
        a = bfpair(hs.w); b = bfpair(hd.w);
        p = fmaf(a.x, b.x, p); p = fmaf(a.y, b.y, p);
    }
    // pos rows: 32 f32 = 128 B; lane j takes float4 #j
    float4 pa = ((const float4*)(pos + (size_t)src * POS_DIM))[j];
    float4 pb = ((const float4*)(pos + (size_t)dst * POS_DIM))[j];
    float dx = pa.x - pb.x, dy = pa.y - pb.y, dz = pa.z - pb.z, dw = pa.w - pb.w;
    float pe = 0.0f;
    pe = fmaf(dx, dx, pe); pe = fmaf(dy, dy, pe);
    pe = fmaf(dz, dz, pe); pe = fmaf(dw, dw, pe);
    p  += __shfl_xor(p, 1);  pe += __shfl_xor(pe, 1);
    p  += __shfl_xor(p, 2);  pe += __shfl_xor(pe, 2);
    p  += __shfl_xor(p, 4);  pe += __shfl_xor(pe, 4);
    if (j == 0) out[e] = fcw[0] * p + fcw[1] * pe + fcb[0];
}

static inline size_t align16(size_t v) { return (v + 15) & ~(size_t)15; }

extern "C" void kernel_launch(void* const* d_in, const int* in_sizes, int n_in,
                              void* d_out, int out_size, void* d_ws, size_t ws_size,
                              hipStream_t stream) {
    const float* x    = (const float*)d_in[0];
    const float* pos  = (const float*)d_in[1];
    const int*   pei  = (const int*)d_in[2];
    const int*   nei  = (const int*)d_in[3];
    const int*   tp   = (const int*)d_in[4];
    const float* W1   = (const float*)d_in[5];
    const float* b1   = (const float*)d_in[6];
    const float* em1w = (const float*)d_in[7];
    const float* em1b = (const float*)d_in[8];
    const float* W2   = (const float*)d_in[9];
    const float* b2   = (const float*)d_in[10];
    const float* em2w = (const float*)d_in[11];
    const float* em2b = (const float*)d_in[12];
    const float* fcw  = (const float*)d_in[13];
    const float* fcb  = (const float*)d_in[14];
    float* outp = (float*)d_out;

    const int N   = in_sizes[0] / IN_DIM;   // 50000
    const int E   = in_sizes[4] / 2;        // 800000
    const int Elp = in_sizes[2] / 2;        // 100000
    const int NB  = (N + 255) / 256;

    char* base = (char*)d_ws;
    size_t o = 0;
    int4* csr = (int4*)(base + o);          o += align16((size_t)E * 16);
    int*   cnt  = (int*)(base + o);         o += align16((size_t)N * 4);
    int*   off  = (int*)(base + o);         o += align16((size_t)(N + 1) * 4);
    int*   bsum = (int*)(base + o);         o += align16((size_t)NB * 4);
    float* dinv = (float*)(base + o);       o += align16((size_t)N * 4);
    float* obuf = (float*)(base + o);       o += align16((size_t)N * HID * 4);
    // rank/sq (2E ints/floats) alias hbuf (N*HID ushort) — rank,sq dead before gemm1
    char*  region = base + o;
    int*   rank = (int*)region;
    float* sq   = (float*)(region + align16((size_t)E * 4));
    unsigned short* hbuf = (unsigned short*)region;

    // ---- CSR build ----
    hipMemsetAsync(cnt, 0, (size_t)N * 4, stream);
    k_pre<<<(E + 31) / 32, 256, 0, stream>>>(tp, pos, cnt, sq, rank, E);
    k_bsum<<<NB, 256, 0, stream>>>(cnt, bsum, N);
    k_scan2<<<NB, 256, 0, stream>>>(cnt, bsum, off, dinv, N, E);
    k_fill<<<(E + 255) / 256, 256, 0, stream>>>(tp, off, rank, sq, dinv,
                                                em1w, em1b, em2w, em2b, csr, E);

    // ---- layer 1 ----
    k_gemm<IN_DIM><<<(N + 31) / 32, 256, 0, stream>>>(x, W1, hbuf, N);
    k_agg<false><<<(N + 3) / 4, 256, 0, stream>>>(off, csr, hbuf, dinv, b1, em1b, obuf, N, 0);

    // ---- layer 2 ----
    k_gemm<HID><<<(N + 31) / 32, 256, 0, stream>>>(obuf, W2, hbuf, N);
    k_agg<true><<<(N + 3) / 4, 256, 0, stream>>>(off, csr, hbuf, dinv, b2, em2b,
                                                 (void*)obuf, N, 1);

    // ---- predictor: layer-2 output is bf16 in obuf ----
    k_predict<<<(2 * Elp + 31) / 32, 256, 0, stream>>>(pei, nei, (const unsigned short*)obuf,
                                                       pos, fcw, fcb, outp, Elp);
}

// Round 8
// 189.857 us; speedup vs baseline: 3.1926x; 1.1481x over previous
//
#include <hip/hip_runtime.h>

#define HID 64
#define POS_DIM 32
#define IN_DIM 128

using short8 = __attribute__((ext_vector_type(8))) short;
using f32x4  = __attribute__((ext_vector_type(4))) float;

__device__ __forceinline__ float fsig(float v) {
    return 1.0f / (1.0f + __expf(-v));
}

// round-to-nearest-even fp32 -> bf16 bits
__device__ __forceinline__ unsigned short f2bf(float f) {
    unsigned int u = __float_as_uint(f);
    u = u + 0x7FFFu + ((u >> 16) & 1u);
    return (unsigned short)(u >> 16);
}
__device__ __forceinline__ float bf2f(unsigned short s) {
    return __uint_as_float(((unsigned int)s) << 16);
}
__device__ __forceinline__ float2 bfpair(unsigned int u) {
    return make_float2(__uint_as_float(u << 16),
                       __uint_as_float(u & 0xFFFF0000u));
}
__device__ __forceinline__ unsigned int pack2bf(float a, float b) {
    return (unsigned int)f2bf(a) | ((unsigned int)f2bf(b) << 16);
}

// ---------------- pass A: sqdist + rank + in-degree histogram ----------------
__global__ __launch_bounds__(256) void k_pre(const int* __restrict__ tp,
                                             const float* __restrict__ pos,
                                             int* cnt, float* __restrict__ sq,
                                             int* __restrict__ rank, int E) {
    int lane = threadIdx.x & 63;
    int wid  = threadIdx.x >> 6;
    int sub  = lane >> 3;
    int j    = lane & 7;
    int e = (blockIdx.x * 4 + wid) * 8 + sub;
    if (e >= E) return;
    int row = tp[e];
    int col = tp[E + e];
    float4 a = ((const float4*)(pos + (size_t)row * POS_DIM))[j];
    float4 b = ((const float4*)(pos + (size_t)col * POS_DIM))[j];
    float dx = a.x - b.x, dy = a.y - b.y, dz = a.z - b.z, dw = a.w - b.w;
    float s = 0.0f;
    s = fmaf(dx, dx, s); s = fmaf(dy, dy, s);
    s = fmaf(dz, dz, s); s = fmaf(dw, dw, s);
    s += __shfl_xor(s, 1);
    s += __shfl_xor(s, 2);
    s += __shfl_xor(s, 4);
    if (j == 0) {
        sq[e] = s;
        rank[e] = atomicAdd(&cnt[col], 1);
    }
}

// ---------------- scan phase 1 ----------------
__global__ __launch_bounds__(256) void k_bsum(const int* __restrict__ cnt,
                                              int* __restrict__ bsum, int n) {
    int i = blockIdx.x * 256 + threadIdx.x;
    int v = (i < n) ? cnt[i] : 0;
    #pragma unroll
    for (int o = 32; o; o >>= 1) v += __shfl_down(v, o);
    __shared__ int w[4];
    int lane = threadIdx.x & 63, wid = threadIdx.x >> 6;
    if (lane == 0) w[wid] = v;
    __syncthreads();
    if (threadIdx.x == 0) bsum[blockIdx.x] = w[0] + w[1] + w[2] + w[3];
}

// ---------------- scan phase 2 ----------------
__global__ __launch_bounds__(256) void k_scan2(const int* __restrict__ cnt,
                                               const int* __restrict__ bsum,
                                               int* __restrict__ off,
                                               float* __restrict__ dinv,
                                               int n, int Etot) {
    __shared__ int s[256];
    __shared__ int wsum[4];
    int tid = threadIdx.x, bid = blockIdx.x;
    int p = 0;
    for (int t = tid; t < bid; t += 256) p += bsum[t];
    #pragma unroll
    for (int o = 32; o; o >>= 1) p += __shfl_down(p, o);
    int lane = tid & 63, wid = tid >> 6;
    if (lane == 0) wsum[wid] = p;
    __syncthreads();
    int bpre = wsum[0] + wsum[1] + wsum[2] + wsum[3];
    int i = bid * 256 + tid;
    int v = (i < n) ? cnt[i] : 0;
    s[tid] = v;
    __syncthreads();
    #pragma unroll
    for (int d = 1; d < 256; d <<= 1) {
        int t_ = (tid >= d) ? s[tid - d] : 0;
        __syncthreads();
        s[tid] += t_;
        __syncthreads();
    }
    if (i < n) {
        off[i]  = bpre + s[tid] - v;
        dinv[i] = rsqrtf((float)(v + 1));
    }
    if (i == 0) off[n] = Etot;
}

// ---------------- pass B: CSR fill — int4{row, c1bits, c2bits, 0} ----------------
__global__ __launch_bounds__(256) void k_fill(const int* __restrict__ tp,
                                              const int* __restrict__ off,
                                              const int* __restrict__ rank,
                                              const float* __restrict__ sq,
                                              const float* __restrict__ dinv,
                                              const float* em1w, const float* em1b,
                                              const float* em2w, const float* em2b,
                                              int4* __restrict__ csr, int E) {
    int e = blockIdx.x * blockDim.x + threadIdx.x;
    if (e >= E) return;
    int row = tp[e];
    int col = tp[E + e];
    int slot = off[col] + rank[e];
    float nrm = dinv[row] * dinv[col];
    float s = sq[e];
    float c1 = fsig(s * em1w[0] + em1b[0]) * nrm;
    float c2 = fsig(s * em2w[0] + em2b[0]) * nrm;
    csr[slot] = make_int4(row, __float_as_int(c1), __float_as_int(c2), 0);
}

// ---------------- MFMA GEMM: H[n,64] = X[n,K] @ W[K,64], bf16 out ----------------
// 64-row x 64-col tile per block; 4 waves, wave w owns rows [16w,16w+16).
// LDS: A[64][K] bf16 + Wt[64][K] bf16 (W transposed), XOR chunk-swizzled.
template<int K, bool IN_BF16>
__global__ __launch_bounds__(256) void k_gemm_mfma(const void* __restrict__ Xv,
                                                   const float* __restrict__ W,
                                                   unsigned short* __restrict__ H,
                                                   int n) {
    constexpr int RB   = K * 2;        // row bytes
    constexpr int CPR  = K / 8;        // 16B chunks per row
    __shared__ unsigned char lds[64 * RB * 2];
    unsigned char* As = lds;
    unsigned char* Bt = lds + 64 * RB;

    int tid  = threadIdx.x;
    int row0 = blockIdx.x * 64;

    // ---- stage A: X rows -> bf16, swizzled ----
    for (int i = tid; i < 64 * CPR; i += 256) {
        int r  = i / CPR;
        int kb = i % CPR;
        uint4 val;
        if (row0 + r < n) {
            if (IN_BF16) {
                val = *(const uint4*)((const unsigned short*)Xv + (size_t)(row0 + r) * K + kb * 8);
            } else {
                const float* src = (const float*)Xv + (size_t)(row0 + r) * K + kb * 8;
                float4 f0 = ((const float4*)src)[0];
                float4 f1 = ((const float4*)src)[1];
                val.x = pack2bf(f0.x, f0.y); val.y = pack2bf(f0.z, f0.w);
                val.z = pack2bf(f1.x, f1.y); val.w = pack2bf(f1.z, f1.w);
            }
        } else {
            val = make_uint4(0, 0, 0, 0);
        }
        *(uint4*)(As + r * RB + ((kb ^ (r & 7)) << 4)) = val;
    }
    // ---- stage W^T: W[K][64] fp32 -> Bt[64][K] bf16, swizzled ----
    for (int i = tid; i < K * 16; i += 256) {
        int k  = i / 16;
        int c0 = (i % 16) * 4;
        float4 w = ((const float4*)W)[i];
        #pragma unroll
        for (int u = 0; u < 4; ++u) {
            int c = c0 + u;
            float vv = (u == 0) ? w.x : (u == 1) ? w.y : (u == 2) ? w.z : w.w;
            int byte = c * RB + ((((k * 2) >> 4) ^ (c & 7)) << 4) + ((k & 7) * 2);
            *(unsigned short*)(Bt + byte) = f2bf(vv);
        }
    }
    __syncthreads();

    int wv   = tid >> 6;
    int lane = tid & 63;
    int l15  = lane & 15;
    int g    = lane >> 4;

    f32x4 acc[4] = {{0,0,0,0},{0,0,0,0},{0,0,0,0},{0,0,0,0}};
    #pragma unroll
    for (int kk = 0; kk < K / 32; ++kk) {
        int kc = kk * 4 + g;
        int arow = wv * 16 + l15;
        short8 a = *(const short8*)(As + arow * RB + ((kc ^ (arow & 7)) << 4));
        #pragma unroll
        for (int cb = 0; cb < 4; ++cb) {
            int c = cb * 16 + l15;
            short8 b = *(const short8*)(Bt + c * RB + ((kc ^ (c & 7)) << 4));
            acc[cb] = __builtin_amdgcn_mfma_f32_16x16x32_bf16(a, b, acc[cb], 0, 0, 0);
        }
    }

    // C/D layout: col = lane&15, row = (lane>>4)*4 + reg
    #pragma unroll
    for (int cb = 0; cb < 4; ++cb) {
        #pragma unroll
        for (int r = 0; r < 4; ++r) {
            int row = row0 + wv * 16 + g * 4 + r;
            if (row < n) H[(size_t)row * HID + cb * 16 + l15] = f2bf(acc[cb][r]);
        }
    }
}

// ---------------- gather-aggregate (bias + self-loop + edge sum), bf16 h ----------------
template<bool BF16OUT>
__global__ __launch_bounds__(256) void k_agg(const int* __restrict__ off,
                                             const int4* __restrict__ csr,
                                             const unsigned short* __restrict__ h,
                                             const float* __restrict__ dinv,
                                             const float* __restrict__ bias,
                                             const float* emb,
                                             void* __restrict__ outv, int n,
                                             int layer) {
    int wid  = threadIdx.x >> 6;
    int lane = threadIdx.x & 63;
    int i = blockIdx.x * 4 + wid;
    if (i >= n) return;
    float di = dinv[i];
    float gself = fsig(emb[0]);
    float acc = bias[lane] + gself * di * di * bf2f(h[(size_t)i * HID + lane]);
    int s = off[i], s1 = off[i + 1];
    for (; s + 4 <= s1; s += 4) {
        int4 e0 = csr[s],     e1 = csr[s + 1];
        int4 e2 = csr[s + 2], e3 = csr[s + 3];
        float c0 = __int_as_float(layer ? e0.z : e0.y);
        float c1 = __int_as_float(layer ? e1.z : e1.y);
        float c2 = __int_as_float(layer ? e2.z : e2.y);
        float c3 = __int_as_float(layer ? e3.z : e3.y);
        float v0 = bf2f(h[(size_t)e0.x * HID + lane]);
        float v1 = bf2f(h[(size_t)e1.x * HID + lane]);
        float v2 = bf2f(h[(size_t)e2.x * HID + lane]);
        float v3 = bf2f(h[(size_t)e3.x * HID + lane]);
        acc = fmaf(c0, v0, acc); acc = fmaf(c1, v1, acc);
        acc = fmaf(c2, v2, acc); acc = fmaf(c3, v3, acc);
    }
    for (; s < s1; ++s) {
        int4 e0 = csr[s];
        acc = fmaf(__int_as_float(layer ? e0.z : e0.y),
                   bf2f(h[(size_t)e0.x * HID + lane]), acc);
    }
    if (BF16OUT) ((unsigned short*)outv)[(size_t)i * HID + lane] = f2bf(acc);
    else         ((float*)outv)[(size_t)i * HID + lane] = acc;
}

// ---------------- final link predictor: 8 lanes per edge, bf16 h ----------------
__global__ __launch_bounds__(256) void k_predict(const int* __restrict__ pei,
                                                 const int* __restrict__ nei,
                                                 const unsigned short* __restrict__ h,
                                                 const float* __restrict__ pos,
                                                 const float* fcw, const float* fcb,
                                                 float* __restrict__ out, int Elp) {
    int j = threadIdx.x & 7;
    int e = blockIdx.x * 32 + (threadIdx.x >> 3);
    if (e >= 2 * Elp) return;
    int src, dst;
    if (e < Elp) { src = pei[e];        dst = pei[Elp + e]; }
    else         { src = nei[e - Elp];  dst = nei[e];       }
    uint4 hs = ((const uint4*)(h + (size_t)src * HID))[j];
    uint4 hd = ((const uint4*)(h + (size_t)dst * HID))[j];
    float p = 0.0f;
    {
        float2 a, b;
        a = bfpair(hs.x); b = bfpair(hd.x);
        p = fmaf(a.x, b.x, p); p = fmaf(a.y, b.y, p);
        a = bfpair(hs.y); b = bfpair(hd.y);
        p = fmaf(a.x, b.x, p); p = fmaf(a.y, b.y, p);
        a = bfpair(hs.z); b = bfpair(hd.z);
        p = fmaf(a.x, b.x, p); p = fmaf(a.y, b.y, p);
        a = bfpair(hs.w); b = bfpair(hd.w);
        p = fmaf(a.x, b.x, p); p = fmaf(a.y, b.y, p);
    }
    float4 pa = ((const float4*)(pos + (size_t)src * POS_DIM))[j];
    float4 pb = ((const float4*)(pos + (size_t)dst * POS_DIM))[j];
    float dx = pa.x - pb.x, dy = pa.y - pb.y, dz = pa.z - pb.z, dw = pa.w - pb.w;
    float pe = 0.0f;
    pe = fmaf(dx, dx, pe); pe = fmaf(dy, dy, pe);
    pe = fmaf(dz, dz, pe); pe = fmaf(dw, dw, pe);
    p  += __shfl_xor(p, 1);  pe += __shfl_xor(pe, 1);
    p  += __shfl_xor(p, 2);  pe += __shfl_xor(pe, 2);
    p  += __shfl_xor(p, 4);  pe += __shfl_xor(pe, 4);
    if (j == 0) out[e] = fcw[0] * p + fcw[1] * pe + fcb[0];
}

static inline size_t align16(size_t v) { return (v + 15) & ~(size_t)15; }

extern "C" void kernel_launch(void* const* d_in, const int* in_sizes, int n_in,
                              void* d_out, int out_size, void* d_ws, size_t ws_size,
                              hipStream_t stream) {
    const float* x    = (const float*)d_in[0];
    const float* pos  = (const float*)d_in[1];
    const int*   pei  = (const int*)d_in[2];
    const int*   nei  = (const int*)d_in[3];
    const int*   tp   = (const int*)d_in[4];
    const float* W1   = (const float*)d_in[5];
    const float* b1   = (const float*)d_in[6];
    const float* em1w = (const float*)d_in[7];
    const float* em1b = (const float*)d_in[8];
    const float* W2   = (const float*)d_in[9];
    const float* b2   = (const float*)d_in[10];
    const float* em2w = (const float*)d_in[11];
    const float* em2b = (const float*)d_in[12];
    const float* fcw  = (const float*)d_in[13];
    const float* fcb  = (const float*)d_in[14];
    float* outp = (float*)d_out;

    const int N   = in_sizes[0] / IN_DIM;   // 50000
    const int E   = in_sizes[4] / 2;        // 800000
    const int Elp = in_sizes[2] / 2;        // 100000
    const int NB  = (N + 255) / 256;

    char* base = (char*)d_ws;
    size_t o = 0;
    int4* csr = (int4*)(base + o);          o += align16((size_t)E * 16);
    int*   cnt  = (int*)(base + o);         o += align16((size_t)N * 4);
    int*   off  = (int*)(base + o);         o += align16((size_t)(N + 1) * 4);
    int*   bsum = (int*)(base + o);         o += align16((size_t)NB * 4);
    float* dinv = (float*)(base + o);       o += align16((size_t)N * 4);
    // obuf region: N*HID fp32-sized; holds bf16 agg outputs (half used)
    unsigned short* obuf = (unsigned short*)(base + o); o += align16((size_t)N * HID * 4);
    // rank/sq (2E ints/floats) alias hbuf (N*HID ushort) — rank,sq dead before gemm1
    char*  region = base + o;
    int*   rank = (int*)region;
    float* sq   = (float*)(region + align16((size_t)E * 4));
    unsigned short* hbuf = (unsigned short*)region;

    // ---- CSR build ----
    hipMemsetAsync(cnt, 0, (size_t)N * 4, stream);
    k_pre<<<(E + 31) / 32, 256, 0, stream>>>(tp, pos, cnt, sq, rank, E);
    k_bsum<<<NB, 256, 0, stream>>>(cnt, bsum, N);
    k_scan2<<<NB, 256, 0, stream>>>(cnt, bsum, off, dinv, N, E);
    k_fill<<<(E + 255) / 256, 256, 0, stream>>>(tp, off, rank, sq, dinv,
                                                em1w, em1b, em2w, em2b, csr, E);

    // ---- layer 1 ----
    k_gemm_mfma<IN_DIM, false><<<(N + 63) / 64, 256, 0, stream>>>(x, W1, hbuf, N);
    k_agg<true><<<(N + 3) / 4, 256, 0, stream>>>(off, csr, hbuf, dinv, b1, em1b,
                                                 (void*)obuf, N, 0);

    // ---- layer 2 ----
    k_gemm_mfma<HID, true><<<(N + 63) / 64, 256, 0, stream>>>(obuf, W2, hbuf, N);
    k_agg<true><<<(N + 3) / 4, 256, 0, stream>>>(off, csr, hbuf, dinv, b2, em2b,
                                                 (void*)obuf, N, 1);

    // ---- predictor: layer-2 output is bf16 in obuf ----
    k_predict<<<(2 * Elp + 31) / 32, 256, 0, stream>>>(pei, nei, obuf,
                                                       pos, fcw, fcb, outp, Elp);
}